// Round 1
// baseline (2058.484 us; speedup 1.0000x reference)
//
#include <hip/hip_runtime.h>
#include <hip/hip_bf16.h>

// Problem constants (validated against in_sizes at runtime via division).
#define H 64

// ---------------------------------------------------------------------------
// Edge aggregation, layer 1: per edge e (wave of 64 lanes, lane = channel c):
//   accD[dst][c] += gene[src][c];  accG[src][c] += dis[dst][c];
//   cntD[dst] += 1;  cntG[src] += 1;   (lane 0 only)
// ---------------------------------------------------------------------------
__global__ __launch_bounds__(256) void agg1_kernel(
    const float* __restrict__ gene, const float* __restrict__ dis,
    const int* __restrict__ es, const int* __restrict__ ed,
    float* __restrict__ accD, float* __restrict__ accG,
    float* __restrict__ cntD, float* __restrict__ cntG, int ne)
{
    long long t = (long long)blockIdx.x * blockDim.x + threadIdx.x;
    int e = (int)(t >> 6);
    int lane = (int)(t & 63);
    if (e >= ne) return;
    int s = es[e];
    int d = ed[e];
    float vg = gene[(size_t)s * H + lane];
    float vd = dis[(size_t)d * H + lane];
    atomicAdd(&accD[(size_t)d * H + lane], vg);
    atomicAdd(&accG[(size_t)s * H + lane], vd);
    if (lane == 0) {
        atomicAdd(&cntD[d], 1.0f);
        atomicAdd(&cntG[s], 1.0f);
    }
}

// Layer-2 aggregation: same traversal, sources are layer-1 outputs, no counts.
__global__ __launch_bounds__(256) void agg2_kernel(
    const float* __restrict__ hg, const float* __restrict__ hd,
    const int* __restrict__ es, const int* __restrict__ ed,
    float* __restrict__ accD, float* __restrict__ accG, int ne)
{
    long long t = (long long)blockIdx.x * blockDim.x + threadIdx.x;
    int e = (int)(t >> 6);
    int lane = (int)(t & 63);
    if (e >= ne) return;
    int s = es[e];
    int d = ed[e];
    float vg = hg[(size_t)s * H + lane];
    float vd = hd[(size_t)d * H + lane];
    atomicAdd(&accD[(size_t)d * H + lane], vg);
    atomicAdd(&accG[(size_t)s * H + lane], vd);
}

// ---------------------------------------------------------------------------
// SAGE linear: h[row] = act( (acc[row]/max(cnt,1)) @ wl + xdst[row] @ wr + b )
// In-place: acc becomes h. 16 rows per block, 256 threads:
//   col = tid & 63, quad = tid >> 6; thread handles rows quad, quad+4, +8, +12
// so a wave's 64 lanes share rows (sMean/sX reads broadcast) and read
// consecutive cols of the LDS-staged weights (conflict-free).
// ---------------------------------------------------------------------------
template <bool RELU>
__global__ __launch_bounds__(256) void sage_mm_kernel(
    float* __restrict__ acc, const float* __restrict__ xdst,
    const float* __restrict__ cnt, const float* __restrict__ wl,
    const float* __restrict__ wr, const float* __restrict__ bias, int n)
{
    __shared__ float sWl[H * H];
    __shared__ float sWr[H * H];
    __shared__ float sMean[16][H];
    __shared__ float sX[16][H];
    const int col = threadIdx.x & 63;
    const int quad = threadIdx.x >> 6;  // 0..3
    for (int i = threadIdx.x; i < H * H; i += 256) {
        sWl[i] = wl[i];
        sWr[i] = wr[i];
    }
    const int row0 = blockIdx.x * 16;
    for (int r = quad; r < 16; r += 4) {
        int row = row0 + r;
        if (row < n) {
            float c = fmaxf(cnt[row], 1.0f);
            sMean[r][col] = acc[(size_t)row * H + col] / c;
            sX[r][col] = xdst[(size_t)row * H + col];
        }
    }
    __syncthreads();

    float o0 = bias[col], o1 = o0, o2 = o0, o3 = o0;
    #pragma unroll
    for (int k = 0; k < H; ++k) {
        float wlv = sWl[k * H + col];
        float wrv = sWr[k * H + col];
        o0 += sMean[quad +  0][k] * wlv + sX[quad +  0][k] * wrv;
        o1 += sMean[quad +  4][k] * wlv + sX[quad +  4][k] * wrv;
        o2 += sMean[quad +  8][k] * wlv + sX[quad +  8][k] * wrv;
        o3 += sMean[quad + 12][k] * wlv + sX[quad + 12][k] * wrv;
    }
    float o[4] = {o0, o1, o2, o3};
    #pragma unroll
    for (int rr = 0; rr < 4; ++rr) {
        int row = row0 + quad + rr * 4;
        if (row < n) {
            float v = o[rr];
            if (RELU) v = fmaxf(v, 0.0f);
            acc[(size_t)row * H + col] = v;
        }
    }
}

// ---------------------------------------------------------------------------
// Classifier: out[e] = sum_c hg2[ls[e]][c] * hd2[ld[e]][c]
// wave-per-edge, shuffle reduction.
// ---------------------------------------------------------------------------
__global__ __launch_bounds__(256) void classify_kernel(
    const float* __restrict__ hg2, const float* __restrict__ hd2,
    const int* __restrict__ ls, const int* __restrict__ ld,
    float* __restrict__ out, int nl)
{
    long long t = (long long)blockIdx.x * blockDim.x + threadIdx.x;
    int e = (int)(t >> 6);
    int lane = (int)(t & 63);
    if (e >= nl) return;
    int a = ls[e];
    int b = ld[e];
    float v = hg2[(size_t)a * H + lane] * hd2[(size_t)b * H + lane];
    #pragma unroll
    for (int off = 32; off > 0; off >>= 1) v += __shfl_down(v, off, 64);
    if (lane == 0) out[e] = v;
}

extern "C" void kernel_launch(void* const* d_in, const int* in_sizes, int n_in,
                              void* d_out, int out_size, void* d_ws, size_t ws_size,
                              hipStream_t stream)
{
    const float* gene  = (const float*)d_in[0];
    const float* dis   = (const float*)d_in[1];
    const float* w1gdl = (const float*)d_in[2];
    const float* w1gdr = (const float*)d_in[3];
    const float* w1dgl = (const float*)d_in[4];
    const float* w1dgr = (const float*)d_in[5];
    const float* w2gdl = (const float*)d_in[6];
    const float* w2gdr = (const float*)d_in[7];
    const float* w2dgl = (const float*)d_in[8];
    const float* w2dgr = (const float*)d_in[9];
    const float* b1gd  = (const float*)d_in[10];
    const float* b1dg  = (const float*)d_in[11];
    const float* b2gd  = (const float*)d_in[12];
    const float* b2dg  = (const float*)d_in[13];
    const int* es = (const int*)d_in[14];
    const int* ed = (const int*)d_in[15];
    const int* ls = (const int*)d_in[16];
    const int* ld = (const int*)d_in[17];

    const int ng = in_sizes[0] / H;   // 100000
    const int nd = in_sizes[1] / H;   // 30000
    const int ne = in_sizes[14];      // 1500000
    const int nl = in_sizes[16];      // 500000

    // Workspace layout (floats):
    float* accD1 = (float*)d_ws;                   // nd*H   -> becomes h_d
    float* accG1 = accD1 + (size_t)nd * H;         // ng*H   -> becomes h_g
    float* cntD  = accG1 + (size_t)ng * H;         // nd
    float* cntG  = cntD + nd;                      // ng
    float* accD2 = cntG + ng;                      // nd*H   -> becomes h_d2
    float* accG2 = accD2 + (size_t)nd * H;         // ng*H   -> becomes h_g2
    float* wsEnd = accG2 + (size_t)ng * H;
    size_t zero_bytes = (size_t)((char*)wsEnd - (char*)d_ws);

    hipMemsetAsync(d_ws, 0, zero_bytes, stream);

    // Layer 1 aggregation (+ degree counts)
    {
        long long threads = (long long)ne * 64;
        int blocks = (int)((threads + 255) / 256);
        agg1_kernel<<<blocks, 256, 0, stream>>>(gene, dis, es, ed,
                                                accD1, accG1, cntD, cntG, ne);
    }
    // Layer 1 linear + ReLU (in-place acc -> h)
    sage_mm_kernel<true><<<(nd + 15) / 16, 256, 0, stream>>>(
        accD1, dis, cntD, w1gdl, w1gdr, b1gd, nd);
    sage_mm_kernel<true><<<(ng + 15) / 16, 256, 0, stream>>>(
        accG1, gene, cntG, w1dgl, w1dgr, b1dg, ng);

    // Layer 2 aggregation (sources: h_g, h_d)
    {
        long long threads = (long long)ne * 64;
        int blocks = (int)((threads + 255) / 256);
        agg2_kernel<<<blocks, 256, 0, stream>>>(accG1, accD1, es, ed,
                                                accD2, accG2, ne);
    }
    // Layer 2 linear (no activation)
    sage_mm_kernel<false><<<(nd + 15) / 16, 256, 0, stream>>>(
        accD2, accD1, cntD, w2gdl, w2gdr, b2gd, nd);
    sage_mm_kernel<false><<<(ng + 15) / 16, 256, 0, stream>>>(
        accG2, accG1, cntG, w2dgl, w2dgr, b2dg, ng);

    // Classifier over label edges
    {
        long long threads = (long long)nl * 64;
        int blocks = (int)((threads + 255) / 256);
        classify_kernel<<<blocks, 256, 0, stream>>>(accG2, accD2, ls, ld,
                                                    (float*)d_out, nl);
    }
}

// Round 2
// 1151.282 us; speedup vs baseline: 1.7880x; 1.7880x over previous
//
#include <hip/hip_runtime.h>
#include <hip/hip_bf16.h>

#define H 64

// ---------------------------------------------------------------------------
// CSR build step 1: degree histogram (int atomics on 520 KB, L2-resident).
// ---------------------------------------------------------------------------
__global__ __launch_bounds__(256) void hist_kernel(
    const int* __restrict__ es, const int* __restrict__ ed,
    int* __restrict__ cntD, int* __restrict__ cntG, int ne)
{
    int e = blockIdx.x * blockDim.x + threadIdx.x;
    if (e < ne) {
        atomicAdd(&cntG[es[e]], 1);
        atomicAdd(&cntD[ed[e]], 1);
    }
}

// ---------------------------------------------------------------------------
// CSR build step 2: exclusive scan. grid=2: block 0 scans D, block 1 scans G.
// Single block of 1024 threads, wave-shuffle scan + 16-wave LDS combine.
// Writes row[] (kept) and pos[] (consumed by scatter).
// ---------------------------------------------------------------------------
__global__ __launch_bounds__(1024) void scan_kernel(
    const int* __restrict__ cntD, int* __restrict__ rowD, int* __restrict__ posD, int nd,
    const int* __restrict__ cntG, int* __restrict__ rowG, int* __restrict__ posG, int ng)
{
    const int* cnt; int* row; int* pos; int n;
    if (blockIdx.x == 0) { cnt = cntD; row = rowD; pos = posD; n = nd; }
    else                 { cnt = cntG; row = rowG; pos = posG; n = ng; }

    __shared__ int warpSums[16];
    __shared__ int sCarry;
    const int tid = threadIdx.x;
    const int lane = tid & 63;
    const int wid = tid >> 6;
    if (tid == 0) sCarry = 0;
    __syncthreads();

    for (int base = 0; base < n; base += 1024) {
        int i = base + tid;
        int x = (i < n) ? cnt[i] : 0;
        // inclusive wave scan
        int v = x;
        #pragma unroll
        for (int off = 1; off < 64; off <<= 1) {
            int u = __shfl_up(v, off, 64);
            if (lane >= off) v += u;
        }
        if (lane == 63) warpSums[wid] = v;
        __syncthreads();                       // A: warpSums populated
        if (wid == 0 && lane < 16) {
            int w = warpSums[lane];
            #pragma unroll
            for (int off = 1; off < 16; off <<= 1) {
                int u = __shfl_up(w, off, 64);
                if (lane >= off) w += u;
            }
            warpSums[lane] = w;
        }
        __syncthreads();                       // B: warpSums scanned
        int waveOff = (wid == 0) ? 0 : warpSums[wid - 1];
        int excl = sCarry + waveOff + (v - x);
        if (i < n) { row[i] = excl; pos[i] = excl; }
        __syncthreads();                       // C: everyone read sCarry
        if (tid == 0) sCarry += warpSums[15];
        __syncthreads();                       // D: sCarry updated, warpSums free
    }
    if (tid == 0) row[n] = sCarry;
}

// ---------------------------------------------------------------------------
// CSR build step 3: scatter edge endpoints into both CSRs.
// ---------------------------------------------------------------------------
__global__ __launch_bounds__(256) void scatter_kernel(
    const int* __restrict__ es, const int* __restrict__ ed,
    int* __restrict__ posD, int* __restrict__ posG,
    int* __restrict__ idxD, int* __restrict__ idxG, int ne)
{
    int e = blockIdx.x * blockDim.x + threadIdx.x;
    if (e < ne) {
        int s = es[e], d = ed[e];
        idxD[atomicAdd(&posD[d], 1)] = s;
        idxG[atomicAdd(&posG[s], 1)] = d;
    }
}

// ---------------------------------------------------------------------------
// Gather-mean for BOTH node sets in one launch. Wave per node, lane = channel.
// No atomics: each output row written exactly once. Unroll-2 for MLP-load ILP.
// ---------------------------------------------------------------------------
__global__ __launch_bounds__(256) void gather_mean_kernel(
    const float* __restrict__ srcD, const float* __restrict__ srcG,
    const int* __restrict__ rowD, const int* __restrict__ idxD,
    const int* __restrict__ rowG, const int* __restrict__ idxG,
    float* __restrict__ outD, float* __restrict__ outG, int nd, int ng)
{
    int w = blockIdx.x * 4 + (threadIdx.x >> 6);
    int lane = threadIdx.x & 63;
    const float* src; const int* row; const int* idx; float* out; int node;
    if (w < nd)            { src = srcD; row = rowD; idx = idxD; out = outD; node = w; }
    else if (w < nd + ng)  { src = srcG; row = rowG; idx = idxG; out = outG; node = w - nd; }
    else return;

    int beg = row[node], end = row[node + 1];
    float a0 = 0.0f, a1 = 0.0f;
    int i = beg;
    for (; i + 2 <= end; i += 2) {
        int s0 = idx[i];
        int s1 = idx[i + 1];
        a0 += src[(size_t)s0 * H + lane];
        a1 += src[(size_t)s1 * H + lane];
    }
    if (i < end) a0 += src[(size_t)idx[i] * H + lane];
    float inv = 1.0f / fmaxf((float)(end - beg), 1.0f);
    out[(size_t)node * H + lane] = (a0 + a1) * inv;
}

// ---------------------------------------------------------------------------
// SAGE linear: h[row] = act( mean[row] @ wl + xdst[row] @ wr + b ), in-place
// on mean. 16 rows/block; wave = quad; col = lane. Inner loop vectorized:
// wave-uniform float4 LDS broadcasts (ds_read_b128) for mean/x rows.
// ---------------------------------------------------------------------------
template <bool RELU>
__global__ __launch_bounds__(256) void sage_mm_kernel(
    float* __restrict__ mean, const float* __restrict__ xdst,
    const float* __restrict__ wl, const float* __restrict__ wr,
    const float* __restrict__ bias, int n)
{
    __shared__ float sWl[H * H];
    __shared__ float sWr[H * H];
    __shared__ float sMean[16][H];
    __shared__ float sX[16][H];
    const int col = threadIdx.x & 63;
    const int quad = threadIdx.x >> 6;  // 0..3 (wave id)
    for (int i = threadIdx.x; i < H * H; i += 256) {
        sWl[i] = wl[i];
        sWr[i] = wr[i];
    }
    const int row0 = blockIdx.x * 16;
    for (int r = quad; r < 16; r += 4) {
        int row = row0 + r;
        if (row < n) {
            sMean[r][col] = mean[(size_t)row * H + col];
            sX[r][col]    = xdst[(size_t)row * H + col];
        }
    }
    __syncthreads();

    float o[4];
    o[0] = o[1] = o[2] = o[3] = bias[col];
    #pragma unroll 4
    for (int k = 0; k < H; k += 4) {
        float wlv0 = sWl[(k + 0) * H + col], wrv0 = sWr[(k + 0) * H + col];
        float wlv1 = sWl[(k + 1) * H + col], wrv1 = sWr[(k + 1) * H + col];
        float wlv2 = sWl[(k + 2) * H + col], wrv2 = sWr[(k + 2) * H + col];
        float wlv3 = sWl[(k + 3) * H + col], wrv3 = sWr[(k + 3) * H + col];
        #pragma unroll
        for (int r = 0; r < 4; ++r) {
            float4 m  = *(const float4*)&sMean[quad + 4 * r][k];
            float4 xx = *(const float4*)&sX[quad + 4 * r][k];
            o[r] += m.x * wlv0 + m.y * wlv1 + m.z * wlv2 + m.w * wlv3
                  + xx.x * wrv0 + xx.y * wrv1 + xx.z * wrv2 + xx.w * wrv3;
        }
    }
    #pragma unroll
    for (int r = 0; r < 4; ++r) {
        int row = row0 + quad + r * 4;
        if (row < n) {
            float v = o[r];
            if (RELU) v = fmaxf(v, 0.0f);
            mean[(size_t)row * H + col] = v;
        }
    }
}

// ---------------------------------------------------------------------------
// Classifier: out[e] = sum_c hg2[ls[e]][c] * hd2[ld[e]][c]
// ---------------------------------------------------------------------------
__global__ __launch_bounds__(256) void classify_kernel(
    const float* __restrict__ hg2, const float* __restrict__ hd2,
    const int* __restrict__ ls, const int* __restrict__ ld,
    float* __restrict__ out, int nl)
{
    long long t = (long long)blockIdx.x * blockDim.x + threadIdx.x;
    int e = (int)(t >> 6);
    int lane = (int)(t & 63);
    if (e >= nl) return;
    int a = ls[e];
    int b = ld[e];
    float v = hg2[(size_t)a * H + lane] * hd2[(size_t)b * H + lane];
    #pragma unroll
    for (int off = 32; off > 0; off >>= 1) v += __shfl_down(v, off, 64);
    if (lane == 0) out[e] = v;
}

extern "C" void kernel_launch(void* const* d_in, const int* in_sizes, int n_in,
                              void* d_out, int out_size, void* d_ws, size_t ws_size,
                              hipStream_t stream)
{
    const float* gene  = (const float*)d_in[0];
    const float* dis   = (const float*)d_in[1];
    const float* w1gdl = (const float*)d_in[2];
    const float* w1gdr = (const float*)d_in[3];
    const float* w1dgl = (const float*)d_in[4];
    const float* w1dgr = (const float*)d_in[5];
    const float* w2gdl = (const float*)d_in[6];
    const float* w2gdr = (const float*)d_in[7];
    const float* w2dgl = (const float*)d_in[8];
    const float* w2dgr = (const float*)d_in[9];
    const float* b1gd  = (const float*)d_in[10];
    const float* b1dg  = (const float*)d_in[11];
    const float* b2gd  = (const float*)d_in[12];
    const float* b2dg  = (const float*)d_in[13];
    const int* es = (const int*)d_in[14];
    const int* ed = (const int*)d_in[15];
    const int* ls = (const int*)d_in[16];
    const int* ld = (const int*)d_in[17];

    const int ng = in_sizes[0] / H;   // 100000
    const int nd = in_sizes[1] / H;   // 30000
    const int ne = in_sizes[14];      // 1500000
    const int nl = in_sizes[16];      // 500000

    // Workspace layout (all 4-byte elements):
    int* cntD  = (int*)d_ws;                       // nd
    int* cntG  = cntD + nd;                        // ng
    int* rowD  = cntG + ng;                        // nd+1
    int* rowG  = rowD + nd + 1;                    // ng+1
    int* posD  = rowG + ng + 1;                    // nd
    int* posG  = posD + nd;                        // ng
    int* idxD  = posG + ng;                        // ne
    int* idxG  = idxD + ne;                        // ne
    float* bufD1 = (float*)(idxG + ne);            // nd*H
    float* bufG1 = bufD1 + (size_t)nd * H;         // ng*H
    float* bufD2 = bufG1 + (size_t)ng * H;         // nd*H
    float* bufG2 = bufD2 + (size_t)nd * H;         // ng*H

    // Zero only the histograms (everything else is fully overwritten).
    hipMemsetAsync(cntD, 0, (size_t)(nd + ng) * sizeof(int), stream);

    // CSR build
    hist_kernel<<<(ne + 255) / 256, 256, 0, stream>>>(es, ed, cntD, cntG, ne);
    scan_kernel<<<2, 1024, 0, stream>>>(cntD, rowD, posD, nd,
                                        cntG, rowG, posG, ng);
    scatter_kernel<<<(ne + 255) / 256, 256, 0, stream>>>(es, ed, posD, posG,
                                                         idxD, idxG, ne);

    const int nWaves = nd + ng;
    const int gatherBlocks = (nWaves + 3) / 4;

    // Layer 1: gather means, then linear+ReLU (in-place)
    gather_mean_kernel<<<gatherBlocks, 256, 0, stream>>>(
        gene, dis, rowD, idxD, rowG, idxG, bufD1, bufG1, nd, ng);
    sage_mm_kernel<true><<<(nd + 15) / 16, 256, 0, stream>>>(
        bufD1, dis, w1gdl, w1gdr, b1gd, nd);
    sage_mm_kernel<true><<<(ng + 15) / 16, 256, 0, stream>>>(
        bufG1, gene, w1dgl, w1dgr, b1dg, ng);

    // Layer 2: gather means of h_g/h_d, then linear (no activation)
    gather_mean_kernel<<<gatherBlocks, 256, 0, stream>>>(
        bufG1, bufD1, rowD, idxD, rowG, idxG, bufD2, bufG2, nd, ng);
    sage_mm_kernel<false><<<(nd + 15) / 16, 256, 0, stream>>>(
        bufD2, bufD1, w2gdl, w2gdr, b2gd, nd);
    sage_mm_kernel<false><<<(ng + 15) / 16, 256, 0, stream>>>(
        bufG2, bufG1, w2dgl, w2dgr, b2dg, ng);

    // Classifier
    {
        long long threads = (long long)nl * 64;
        int blocks = (int)((threads + 255) / 256);
        classify_kernel<<<blocks, 256, 0, stream>>>(bufG2, bufD2, ls, ld,
                                                    (float*)d_out, nl);
    }
}

// Round 3
// 833.469 us; speedup vs baseline: 2.4698x; 1.3813x over previous
//
#include <hip/hip_runtime.h>
#include <hip/hip_bf16.h>

#define H 64
#define SCAN_CHUNK 512   // elements per scan block
#define NBANDS 6         // scatter bands: write region/band ~2MB, L2-resident

// ---------------------------------------------------------------------------
// CSR build step 1: degree histogram (int atomics on 520 KB, L2-resident).
// ---------------------------------------------------------------------------
__global__ __launch_bounds__(256) void hist_kernel(
    const int* __restrict__ es, const int* __restrict__ ed,
    int* __restrict__ cntD, int* __restrict__ cntG, int ne)
{
    int e = blockIdx.x * blockDim.x + threadIdx.x;
    if (e < ne) {
        atomicAdd(&cntG[es[e]], 1);
        atomicAdd(&cntD[ed[e]], 1);
    }
}

// ---------------------------------------------------------------------------
// Scan phase A: per-block reduce of SCAN_CHUNK elements.
// Blocks [0,BD) cover cntD, blocks [BD,BD+BG) cover cntG.
// ---------------------------------------------------------------------------
__global__ __launch_bounds__(256) void scan_reduce_kernel(
    const int* __restrict__ cntD, int nd, const int* __restrict__ cntG, int ng,
    int BD, int* __restrict__ partial)
{
    const int b = blockIdx.x;
    const int* cnt; int n, base;
    if (b < BD) { cnt = cntD; n = nd; base = b * SCAN_CHUNK; }
    else        { cnt = cntG; n = ng; base = (b - BD) * SCAN_CHUNK; }
    int t = threadIdx.x;
    int i0 = base + 2 * t, i1 = i0 + 1;
    int v = ((i0 < n) ? cnt[i0] : 0) + ((i1 < n) ? cnt[i1] : 0);
    #pragma unroll
    for (int off = 32; off > 0; off >>= 1) v += __shfl_down(v, off, 64);
    __shared__ int ws[4];
    if ((t & 63) == 0) ws[t >> 6] = v;
    __syncthreads();
    if (t == 0) partial[b] = ws[0] + ws[1] + ws[2] + ws[3];
}

// ---------------------------------------------------------------------------
// Scan phase B: one block scans all partials (<=1024); two segments (D then
// G) via subtract-at-boundary. Writes blockOff, rowD[nd], rowG[ng].
// ---------------------------------------------------------------------------
__global__ __launch_bounds__(1024) void scan_partials_kernel(
    const int* __restrict__ partial, int* __restrict__ blockOff,
    int BD, int nbtot,
    int* __restrict__ rowD, int nd, int* __restrict__ rowG, int ng)
{
    __shared__ int sA[1024], sB[1024];
    int t = threadIdx.x;
    int x = (t < nbtot) ? partial[t] : 0;
    sA[t] = x;
    __syncthreads();
    int* cur = sA; int* nxt = sB;
    for (int off = 1; off < 1024; off <<= 1) {
        int v = cur[t];
        if (t >= off) v += cur[t - off];
        nxt[t] = v;
        __syncthreads();
        int* tmp = cur; cur = nxt; nxt = tmp;
    }
    int incl = cur[t];
    int excl = incl - x;
    int totD = cur[BD - 1];
    if (t < nbtot) blockOff[t] = excl - ((t >= BD) ? totD : 0);
    if (t == 0) rowD[nd] = totD;
    if (t == nbtot - 1) rowG[ng] = incl - totD;
}

// ---------------------------------------------------------------------------
// Scan phase C: per-block exclusive scan of SCAN_CHUNK elems + blockOff;
// writes row[] and pos[].
// ---------------------------------------------------------------------------
__global__ __launch_bounds__(256) void scan_apply_kernel(
    const int* __restrict__ cntD, int* __restrict__ rowD, int* __restrict__ posD, int nd,
    const int* __restrict__ cntG, int* __restrict__ rowG, int* __restrict__ posG, int ng,
    int BD, const int* __restrict__ blockOff)
{
    const int b = blockIdx.x;
    const int* cnt; int* row; int* pos; int n, base;
    if (b < BD) { cnt = cntD; row = rowD; pos = posD; n = nd; base = b * SCAN_CHUNK; }
    else        { cnt = cntG; row = rowG; pos = posG; n = ng; base = (b - BD) * SCAN_CHUNK; }
    int t = threadIdx.x;
    int lane = t & 63, wid = t >> 6;
    int i0 = base + 2 * t, i1 = i0 + 1;
    int x0 = (i0 < n) ? cnt[i0] : 0;
    int x1 = (i1 < n) ? cnt[i1] : 0;
    int p = x0 + x1;
    int P = p;
    #pragma unroll
    for (int off = 1; off < 64; off <<= 1) {
        int u = __shfl_up(P, off, 64);
        if (lane >= off) P += u;
    }
    __shared__ int ws[4];
    if (lane == 63) ws[wid] = P;
    __syncthreads();
    int waveBase = 0;
    #pragma unroll
    for (int w = 0; w < 4; ++w) waveBase += (w < wid) ? ws[w] : 0;
    int off0 = blockOff[b] + waveBase + (P - p);
    if (i0 < n) { row[i0] = off0; pos[i0] = off0; }
    if (i1 < n) { row[i1] = off0 + x0; pos[i1] = off0 + x0; }
}

// ---------------------------------------------------------------------------
// CSR build step 3: banded scatter — pass handles only endpoints in its band,
// keeping the hot write region L2-resident (full-line writebacks).
// ---------------------------------------------------------------------------
__global__ __launch_bounds__(256) void scatter_band_kernel(
    const int* __restrict__ es, const int* __restrict__ ed,
    int* __restrict__ posD, int* __restrict__ posG,
    int* __restrict__ idxD, int* __restrict__ idxG, int ne,
    int dLo, int dHi, int sLo, int sHi)
{
    int e = blockIdx.x * blockDim.x + threadIdx.x;
    if (e >= ne) return;
    int s = es[e], d = ed[e];
    if (d >= dLo && d < dHi) idxD[atomicAdd(&posD[d], 1)] = s;
    if (s >= sLo && s < sHi) idxG[atomicAdd(&posG[s], 1)] = d;
}

// ---------------------------------------------------------------------------
// Gather-mean for BOTH node sets. Wave per node; quarter-wave float4 layout:
// lane = 16*sub + c4 handles edge slot i+sub, channels c4*4..c4*4+3.
// 4 edges x 16 B/lane in flight; xor-shuffle combine across subs at the end.
// ---------------------------------------------------------------------------
__global__ __launch_bounds__(256) void gather_mean_kernel(
    const float* __restrict__ srcD, const float* __restrict__ srcG,
    const int* __restrict__ rowD, const int* __restrict__ idxD,
    const int* __restrict__ rowG, const int* __restrict__ idxG,
    float* __restrict__ outD, float* __restrict__ outG, int nd, int ng)
{
    int w = blockIdx.x * 4 + (threadIdx.x >> 6);
    int lane = threadIdx.x & 63;
    const float* src; const int* row; const int* idx; float* out; int node;
    if (w < nd)            { src = srcD; row = rowD; idx = idxD; out = outD; node = w; }
    else if (w < nd + ng)  { src = srcG; row = rowG; idx = idxG; out = outG; node = w - nd; }
    else return;

    const int sub = lane >> 4;
    const int c4 = (lane & 15) * 4;
    int beg = row[node], end = row[node + 1];

    float4 a0 = make_float4(0.f, 0.f, 0.f, 0.f);
    float4 a1 = make_float4(0.f, 0.f, 0.f, 0.f);
    int i = beg;
    for (; i + 8 <= end; i += 8) {
        int s0 = idx[i + sub];
        int s1 = idx[i + 4 + sub];
        float4 v0 = *(const float4*)&src[(size_t)s0 * H + c4];
        float4 v1 = *(const float4*)&src[(size_t)s1 * H + c4];
        a0.x += v0.x; a0.y += v0.y; a0.z += v0.z; a0.w += v0.w;
        a1.x += v1.x; a1.y += v1.y; a1.z += v1.z; a1.w += v1.w;
    }
    if (i + 4 <= end) {
        int s0 = idx[i + sub];
        float4 v0 = *(const float4*)&src[(size_t)s0 * H + c4];
        a0.x += v0.x; a0.y += v0.y; a0.z += v0.z; a0.w += v0.w;
        i += 4;
    }
    if (i + sub < end) {
        int s1 = idx[i + sub];
        float4 v1 = *(const float4*)&src[(size_t)s1 * H + c4];
        a1.x += v1.x; a1.y += v1.y; a1.z += v1.z; a1.w += v1.w;
    }
    float4 acc = make_float4(a0.x + a1.x, a0.y + a1.y, a0.z + a1.z, a0.w + a1.w);
    #pragma unroll
    for (int m = 16; m <= 32; m <<= 1) {
        acc.x += __shfl_xor(acc.x, m, 64);
        acc.y += __shfl_xor(acc.y, m, 64);
        acc.z += __shfl_xor(acc.z, m, 64);
        acc.w += __shfl_xor(acc.w, m, 64);
    }
    if (sub == 0) {
        float inv = 1.0f / fmaxf((float)(end - beg), 1.0f);
        float4 o = make_float4(acc.x * inv, acc.y * inv, acc.z * inv, acc.w * inv);
        *(float4*)&out[(size_t)node * H + c4] = o;
    }
}

// ---------------------------------------------------------------------------
// SAGE linear: h[row] = act( mean[row] @ wl + xdst[row] @ wr + b ), in-place.
// ---------------------------------------------------------------------------
template <bool RELU>
__global__ __launch_bounds__(256) void sage_mm_kernel(
    float* __restrict__ mean, const float* __restrict__ xdst,
    const float* __restrict__ wl, const float* __restrict__ wr,
    const float* __restrict__ bias, int n)
{
    __shared__ float sWl[H * H];
    __shared__ float sWr[H * H];
    __shared__ float sMean[16][H];
    __shared__ float sX[16][H];
    const int col = threadIdx.x & 63;
    const int quad = threadIdx.x >> 6;
    for (int i = threadIdx.x; i < H * H; i += 256) {
        sWl[i] = wl[i];
        sWr[i] = wr[i];
    }
    const int row0 = blockIdx.x * 16;
    for (int r = quad; r < 16; r += 4) {
        int row = row0 + r;
        if (row < n) {
            sMean[r][col] = mean[(size_t)row * H + col];
            sX[r][col]    = xdst[(size_t)row * H + col];
        }
    }
    __syncthreads();

    float o[4];
    o[0] = o[1] = o[2] = o[3] = bias[col];
    #pragma unroll 4
    for (int k = 0; k < H; k += 4) {
        float wlv0 = sWl[(k + 0) * H + col], wrv0 = sWr[(k + 0) * H + col];
        float wlv1 = sWl[(k + 1) * H + col], wrv1 = sWr[(k + 1) * H + col];
        float wlv2 = sWl[(k + 2) * H + col], wrv2 = sWr[(k + 2) * H + col];
        float wlv3 = sWl[(k + 3) * H + col], wrv3 = sWr[(k + 3) * H + col];
        #pragma unroll
        for (int r = 0; r < 4; ++r) {
            float4 m  = *(const float4*)&sMean[quad + 4 * r][k];
            float4 xx = *(const float4*)&sX[quad + 4 * r][k];
            o[r] += m.x * wlv0 + m.y * wlv1 + m.z * wlv2 + m.w * wlv3
                  + xx.x * wrv0 + xx.y * wrv1 + xx.z * wrv2 + xx.w * wrv3;
        }
    }
    #pragma unroll
    for (int r = 0; r < 4; ++r) {
        int row = row0 + quad + r * 4;
        if (row < n) {
            float v = o[r];
            if (RELU) v = fmaxf(v, 0.0f);
            mean[(size_t)row * H + col] = v;
        }
    }
}

// ---------------------------------------------------------------------------
// Classifier: quarter-wave per edge, float4 loads, xor-shuffle dot reduce.
// ---------------------------------------------------------------------------
__global__ __launch_bounds__(256) void classify_kernel(
    const float* __restrict__ hg2, const float* __restrict__ hd2,
    const int* __restrict__ ls, const int* __restrict__ ld,
    float* __restrict__ out, int nl)
{
    long long t = (long long)blockIdx.x * blockDim.x + threadIdx.x;
    int e = (int)(t >> 4);
    int c4 = (int)(t & 15) * 4;
    if (e >= nl) return;
    int a = ls[e];
    int b = ld[e];
    float4 va = *(const float4*)&hg2[(size_t)a * H + c4];
    float4 vb = *(const float4*)&hd2[(size_t)b * H + c4];
    float v = va.x * vb.x + va.y * vb.y + va.z * vb.z + va.w * vb.w;
    #pragma unroll
    for (int m = 1; m <= 8; m <<= 1) v += __shfl_xor(v, m, 64);
    if (c4 == 0) out[e] = v;
}

extern "C" void kernel_launch(void* const* d_in, const int* in_sizes, int n_in,
                              void* d_out, int out_size, void* d_ws, size_t ws_size,
                              hipStream_t stream)
{
    const float* gene  = (const float*)d_in[0];
    const float* dis   = (const float*)d_in[1];
    const float* w1gdl = (const float*)d_in[2];
    const float* w1gdr = (const float*)d_in[3];
    const float* w1dgl = (const float*)d_in[4];
    const float* w1dgr = (const float*)d_in[5];
    const float* w2gdl = (const float*)d_in[6];
    const float* w2gdr = (const float*)d_in[7];
    const float* w2dgl = (const float*)d_in[8];
    const float* w2dgr = (const float*)d_in[9];
    const float* b1gd  = (const float*)d_in[10];
    const float* b1dg  = (const float*)d_in[11];
    const float* b2gd  = (const float*)d_in[12];
    const float* b2dg  = (const float*)d_in[13];
    const int* es = (const int*)d_in[14];
    const int* ed = (const int*)d_in[15];
    const int* ls = (const int*)d_in[16];
    const int* ld = (const int*)d_in[17];

    const int ng = in_sizes[0] / H;   // 100000
    const int nd = in_sizes[1] / H;   // 30000
    const int ne = in_sizes[14];      // 1500000
    const int nl = in_sizes[16];      // 500000

    // Workspace layout (all 4-byte elements):
    int* cntD  = (int*)d_ws;                       // nd
    int* cntG  = cntD + nd;                        // ng
    int* rowD  = cntG + ng;                        // nd+1
    int* rowG  = rowD + nd + 1;                    // ng+1
    int* posD  = rowG + ng + 1;                    // nd
    int* posG  = posD + nd;                        // ng
    int* idxD  = posG + ng;                        // ne
    int* idxG  = idxD + ne;                        // ne
    int* partial  = idxG + ne;                     // 1024
    int* blockOff = partial + 1024;                // 1024
    float* bufD1 = (float*)(blockOff + 1024);      // nd*H
    float* bufG1 = bufD1 + (size_t)nd * H;         // ng*H
    float* bufD2 = bufG1 + (size_t)ng * H;         // nd*H
    float* bufG2 = bufD2 + (size_t)nd * H;         // ng*H

    hipMemsetAsync(cntD, 0, (size_t)(nd + ng) * sizeof(int), stream);

    // CSR build
    hist_kernel<<<(ne + 255) / 256, 256, 0, stream>>>(es, ed, cntD, cntG, ne);

    const int BD = (nd + SCAN_CHUNK - 1) / SCAN_CHUNK;
    const int BG = (ng + SCAN_CHUNK - 1) / SCAN_CHUNK;
    const int nbtot = BD + BG;   // must be <= 1024
    scan_reduce_kernel<<<nbtot, 256, 0, stream>>>(cntD, nd, cntG, ng, BD, partial);
    scan_partials_kernel<<<1, 1024, 0, stream>>>(partial, blockOff, BD, nbtot,
                                                 rowD, nd, rowG, ng);
    scan_apply_kernel<<<nbtot, 256, 0, stream>>>(cntD, rowD, posD, nd,
                                                 cntG, rowG, posG, ng,
                                                 BD, blockOff);

    for (int b = 0; b < NBANDS; ++b) {
        int dLo = (int)((long long)nd * b / NBANDS);
        int dHi = (int)((long long)nd * (b + 1) / NBANDS);
        int sLo = (int)((long long)ng * b / NBANDS);
        int sHi = (int)((long long)ng * (b + 1) / NBANDS);
        scatter_band_kernel<<<(ne + 255) / 256, 256, 0, stream>>>(
            es, ed, posD, posG, idxD, idxG, ne, dLo, dHi, sLo, sHi);
    }

    const int nWaves = nd + ng;
    const int gatherBlocks = (nWaves + 3) / 4;

    // Layer 1
    gather_mean_kernel<<<gatherBlocks, 256, 0, stream>>>(
        gene, dis, rowD, idxD, rowG, idxG, bufD1, bufG1, nd, ng);
    sage_mm_kernel<true><<<(nd + 15) / 16, 256, 0, stream>>>(
        bufD1, dis, w1gdl, w1gdr, b1gd, nd);
    sage_mm_kernel<true><<<(ng + 15) / 16, 256, 0, stream>>>(
        bufG1, gene, w1dgl, w1dgr, b1dg, ng);

    // Layer 2
    gather_mean_kernel<<<gatherBlocks, 256, 0, stream>>>(
        bufG1, bufD1, rowD, idxD, rowG, idxG, bufD2, bufG2, nd, ng);
    sage_mm_kernel<false><<<(nd + 15) / 16, 256, 0, stream>>>(
        bufD2, bufD1, w2gdl, w2gdr, b2gd, nd);
    sage_mm_kernel<false><<<(ng + 15) / 16, 256, 0, stream>>>(
        bufG2, bufG1, w2dgl, w2dgr, b2dg, ng);

    // Classifier
    {
        long long threads = (long long)nl * 16;
        int blocks = (int)((threads + 255) / 256);
        classify_kernel<<<blocks, 256, 0, stream>>>(bufG2, bufD2, ls, ld,
                                                    (float*)d_out, nl);
    }
}

// Round 4
// 708.034 us; speedup vs baseline: 2.9073x; 1.1772x over previous
//
#include <hip/hip_runtime.h>
#include <hip/hip_bf16.h>

#define H 64
#define SCAN_CHUNK 512   // elements per scan block
#define NBANDS 6         // scatter bands: hot write region/band ~2MB, L2-resident

// ---------------------------------------------------------------------------
// Fused kernel: blocks [0,HB) do the histogram AND record each edge's slot
// (the atomic's return value = within-node position). Remaining blocks compute
// the gather-independent layer-1 self halves: self = x @ wr + b.
// Hist is atomic-throughput-bound (VALUBusy 0.3%) so the mm blocks ride the
// idle VALU/LDS underneath the same dispatch window.
// ---------------------------------------------------------------------------
__global__ __launch_bounds__(256) void fused_hist_selfmm_kernel(
    const int* __restrict__ es, const int* __restrict__ ed,
    int* __restrict__ cntD, int* __restrict__ cntG,
    unsigned short* __restrict__ slotD, unsigned short* __restrict__ slotG, int ne,
    const float* __restrict__ dis, const float* __restrict__ gene,
    const float* __restrict__ w1gdr, const float* __restrict__ b1gd,
    const float* __restrict__ w1dgr, const float* __restrict__ b1dg,
    float* __restrict__ selfD, float* __restrict__ selfG,
    int nd, int ng, int HB, int MBD)
{
    __shared__ float sW[H * H];
    __shared__ float sX[16][H];

    int b = blockIdx.x;
    if (b < HB) {
        int e = b * 256 + threadIdx.x;
        if (e < ne) {
            int s = es[e], d = ed[e];
            slotG[e] = (unsigned short)atomicAdd(&cntG[s], 1);
            slotD[e] = (unsigned short)atomicAdd(&cntD[d], 1);
        }
        return;
    }
    b -= HB;
    const float* x; const float* w; const float* bias; float* out; int n;
    if (b < MBD) { x = dis;  w = w1gdr; bias = b1gd; out = selfD; n = nd; }
    else         { b -= MBD; x = gene; w = w1dgr; bias = b1dg; out = selfG; n = ng; }

    const int col = threadIdx.x & 63;
    const int quad = threadIdx.x >> 6;
    for (int i = threadIdx.x; i < H * H; i += 256) sW[i] = w[i];
    const int row0 = b * 16;
    for (int r = quad; r < 16; r += 4) {
        int row = row0 + r;
        if (row < n) sX[r][col] = x[(size_t)row * H + col];
    }
    __syncthreads();

    float o[4];
    o[0] = o[1] = o[2] = o[3] = bias[col];
    #pragma unroll 4
    for (int k = 0; k < H; k += 4) {
        float w0 = sW[(k + 0) * H + col];
        float w1 = sW[(k + 1) * H + col];
        float w2 = sW[(k + 2) * H + col];
        float w3 = sW[(k + 3) * H + col];
        #pragma unroll
        for (int r = 0; r < 4; ++r) {
            float4 xx = *(const float4*)&sX[quad + 4 * r][k];
            o[r] += xx.x * w0 + xx.y * w1 + xx.z * w2 + xx.w * w3;
        }
    }
    #pragma unroll
    for (int r = 0; r < 4; ++r) {
        int row = row0 + quad + r * 4;
        if (row < n) out[(size_t)row * H + col] = o[r];
    }
}

// ---------------------------------------------------------------------------
// Scan phase A: per-block reduce of SCAN_CHUNK elements.
// ---------------------------------------------------------------------------
__global__ __launch_bounds__(256) void scan_reduce_kernel(
    const int* __restrict__ cntD, int nd, const int* __restrict__ cntG, int ng,
    int BD, int* __restrict__ partial)
{
    const int b = blockIdx.x;
    const int* cnt; int n, base;
    if (b < BD) { cnt = cntD; n = nd; base = b * SCAN_CHUNK; }
    else        { cnt = cntG; n = ng; base = (b - BD) * SCAN_CHUNK; }
    int t = threadIdx.x;
    int i0 = base + 2 * t, i1 = i0 + 1;
    int v = ((i0 < n) ? cnt[i0] : 0) + ((i1 < n) ? cnt[i1] : 0);
    #pragma unroll
    for (int off = 32; off > 0; off >>= 1) v += __shfl_down(v, off, 64);
    __shared__ int ws[4];
    if ((t & 63) == 0) ws[t >> 6] = v;
    __syncthreads();
    if (t == 0) partial[b] = ws[0] + ws[1] + ws[2] + ws[3];
}

// ---------------------------------------------------------------------------
// Scan phase B: one block scans all partials (<=1024).
// ---------------------------------------------------------------------------
__global__ __launch_bounds__(1024) void scan_partials_kernel(
    const int* __restrict__ partial, int* __restrict__ blockOff,
    int BD, int nbtot,
    int* __restrict__ rowD, int nd, int* __restrict__ rowG, int ng)
{
    __shared__ int sA[1024], sB[1024];
    int t = threadIdx.x;
    int x = (t < nbtot) ? partial[t] : 0;
    sA[t] = x;
    __syncthreads();
    int* cur = sA; int* nxt = sB;
    for (int off = 1; off < 1024; off <<= 1) {
        int v = cur[t];
        if (t >= off) v += cur[t - off];
        nxt[t] = v;
        __syncthreads();
        int* tmp = cur; cur = nxt; nxt = tmp;
    }
    int incl = cur[t];
    int excl = incl - x;
    int totD = cur[BD - 1];
    if (t < nbtot) blockOff[t] = excl - ((t >= BD) ? totD : 0);
    if (t == 0) rowD[nd] = totD;
    if (t == nbtot - 1) rowG[ng] = incl - totD;
}

// ---------------------------------------------------------------------------
// Scan phase C: per-block exclusive scan; writes row[].
// ---------------------------------------------------------------------------
__global__ __launch_bounds__(256) void scan_apply_kernel(
    const int* __restrict__ cntD, int* __restrict__ rowD, int nd,
    const int* __restrict__ cntG, int* __restrict__ rowG, int ng,
    int BD, const int* __restrict__ blockOff)
{
    const int b = blockIdx.x;
    const int* cnt; int* row; int n, base;
    if (b < BD) { cnt = cntD; row = rowD; n = nd; base = b * SCAN_CHUNK; }
    else        { cnt = cntG; row = rowG; n = ng; base = (b - BD) * SCAN_CHUNK; }
    int t = threadIdx.x;
    int lane = t & 63, wid = t >> 6;
    int i0 = base + 2 * t, i1 = i0 + 1;
    int x0 = (i0 < n) ? cnt[i0] : 0;
    int x1 = (i1 < n) ? cnt[i1] : 0;
    int p = x0 + x1;
    int P = p;
    #pragma unroll
    for (int off = 1; off < 64; off <<= 1) {
        int u = __shfl_up(P, off, 64);
        if (lane >= off) P += u;
    }
    __shared__ int ws[4];
    if (lane == 63) ws[wid] = P;
    __syncthreads();
    int waveBase = 0;
    #pragma unroll
    for (int w = 0; w < 4; ++w) waveBase += (w < wid) ? ws[w] : 0;
    int off0 = blockOff[b] + waveBase + (P - p);
    if (i0 < n) row[i0] = off0;
    if (i1 < n) row[i1] = off0 + x0;
}

// ---------------------------------------------------------------------------
// Banded scatter — NO atomics: slot was recorded by the hist pass.
// idx[row[key] + slot[e]] = other. row[] reads are tiny L2-resident tables.
// ---------------------------------------------------------------------------
__global__ __launch_bounds__(256) void scatter_band_kernel(
    const int* __restrict__ es, const int* __restrict__ ed,
    const int* __restrict__ rowD, const int* __restrict__ rowG,
    const unsigned short* __restrict__ slotD, const unsigned short* __restrict__ slotG,
    int* __restrict__ idxD, int* __restrict__ idxG, int ne,
    int dLo, int dHi, int sLo, int sHi)
{
    int e = blockIdx.x * blockDim.x + threadIdx.x;
    if (e >= ne) return;
    int s = es[e], d = ed[e];
    if (d >= dLo && d < dHi) idxD[rowD[d] + (int)slotD[e]] = s;
    if (s >= sLo && s < sHi) idxG[rowG[s] + (int)slotG[e]] = d;
}

// ---------------------------------------------------------------------------
// Gather-mean for BOTH node sets. Wave per node; quarter-wave float4 layout;
// main loop 16 edges/iter = 4 independent float4 loads in flight.
// ---------------------------------------------------------------------------
__global__ __launch_bounds__(256) void gather_mean_kernel(
    const float* __restrict__ srcD, const float* __restrict__ srcG,
    const int* __restrict__ rowD, const int* __restrict__ idxD,
    const int* __restrict__ rowG, const int* __restrict__ idxG,
    float* __restrict__ outD, float* __restrict__ outG, int nd, int ng)
{
    int w = blockIdx.x * 4 + (threadIdx.x >> 6);
    int lane = threadIdx.x & 63;
    const float* src; const int* row; const int* idx; float* out; int node;
    if (w < nd)            { src = srcD; row = rowD; idx = idxD; out = outD; node = w; }
    else if (w < nd + ng)  { src = srcG; row = rowG; idx = idxG; out = outG; node = w - nd; }
    else return;

    const int sub = lane >> 4;
    const int c4 = (lane & 15) * 4;
    int beg = row[node], end = row[node + 1];

    float4 a0 = make_float4(0.f, 0.f, 0.f, 0.f);
    float4 a1 = make_float4(0.f, 0.f, 0.f, 0.f);
    float4 a2 = make_float4(0.f, 0.f, 0.f, 0.f);
    float4 a3 = make_float4(0.f, 0.f, 0.f, 0.f);
    int i = beg;
    for (; i + 16 <= end; i += 16) {
        int s0 = idx[i + sub];
        int s1 = idx[i + 4 + sub];
        int s2 = idx[i + 8 + sub];
        int s3 = idx[i + 12 + sub];
        float4 v0 = *(const float4*)&src[(size_t)s0 * H + c4];
        float4 v1 = *(const float4*)&src[(size_t)s1 * H + c4];
        float4 v2 = *(const float4*)&src[(size_t)s2 * H + c4];
        float4 v3 = *(const float4*)&src[(size_t)s3 * H + c4];
        a0.x += v0.x; a0.y += v0.y; a0.z += v0.z; a0.w += v0.w;
        a1.x += v1.x; a1.y += v1.y; a1.z += v1.z; a1.w += v1.w;
        a2.x += v2.x; a2.y += v2.y; a2.z += v2.z; a2.w += v2.w;
        a3.x += v3.x; a3.y += v3.y; a3.z += v3.z; a3.w += v3.w;
    }
    if (i + 8 <= end) {
        int s0 = idx[i + sub];
        int s1 = idx[i + 4 + sub];
        float4 v0 = *(const float4*)&src[(size_t)s0 * H + c4];
        float4 v1 = *(const float4*)&src[(size_t)s1 * H + c4];
        a0.x += v0.x; a0.y += v0.y; a0.z += v0.z; a0.w += v0.w;
        a1.x += v1.x; a1.y += v1.y; a1.z += v1.z; a1.w += v1.w;
        i += 8;
    }
    if (i + 4 <= end) {
        int s0 = idx[i + sub];
        float4 v0 = *(const float4*)&src[(size_t)s0 * H + c4];
        a2.x += v0.x; a2.y += v0.y; a2.z += v0.z; a2.w += v0.w;
        i += 4;
    }
    if (i + sub < end) {
        int s1 = idx[i + sub];
        float4 v1 = *(const float4*)&src[(size_t)s1 * H + c4];
        a3.x += v1.x; a3.y += v1.y; a3.z += v1.z; a3.w += v1.w;
    }
    float4 acc = make_float4((a0.x + a1.x) + (a2.x + a3.x),
                             (a0.y + a1.y) + (a2.y + a3.y),
                             (a0.z + a1.z) + (a2.z + a3.z),
                             (a0.w + a1.w) + (a2.w + a3.w));
    #pragma unroll
    for (int m = 16; m <= 32; m <<= 1) {
        acc.x += __shfl_xor(acc.x, m, 64);
        acc.y += __shfl_xor(acc.y, m, 64);
        acc.z += __shfl_xor(acc.z, m, 64);
        acc.w += __shfl_xor(acc.w, m, 64);
    }
    if (sub == 0) {
        float inv = 1.0f / fmaxf((float)(end - beg), 1.0f);
        float4 o = make_float4(acc.x * inv, acc.y * inv, acc.z * inv, acc.w * inv);
        *(float4*)&out[(size_t)node * H + c4] = o;
    }
}

// ---------------------------------------------------------------------------
// Layer-1 combine: acc = relu(mean @ wl + acc)  (acc holds the precomputed
// self half). Single weight matrix -> half the LDS/FLOPs of full sage_mm.
// ---------------------------------------------------------------------------
__global__ __launch_bounds__(256) void combine_mm_kernel(
    float* __restrict__ acc, const float* __restrict__ mean,
    const float* __restrict__ wl, int n)
{
    __shared__ float sW[H * H];
    __shared__ float sMean[16][H];
    const int col = threadIdx.x & 63;
    const int quad = threadIdx.x >> 6;
    for (int i = threadIdx.x; i < H * H; i += 256) sW[i] = wl[i];
    const int row0 = blockIdx.x * 16;
    for (int r = quad; r < 16; r += 4) {
        int row = row0 + r;
        if (row < n) sMean[r][col] = mean[(size_t)row * H + col];
    }
    __syncthreads();

    float o[4] = {0.f, 0.f, 0.f, 0.f};
    #pragma unroll 4
    for (int k = 0; k < H; k += 4) {
        float w0 = sW[(k + 0) * H + col];
        float w1 = sW[(k + 1) * H + col];
        float w2 = sW[(k + 2) * H + col];
        float w3 = sW[(k + 3) * H + col];
        #pragma unroll
        for (int r = 0; r < 4; ++r) {
            float4 m = *(const float4*)&sMean[quad + 4 * r][k];
            o[r] += m.x * w0 + m.y * w1 + m.z * w2 + m.w * w3;
        }
    }
    #pragma unroll
    for (int r = 0; r < 4; ++r) {
        int row = row0 + quad + r * 4;
        if (row < n) {
            size_t off = (size_t)row * H + col;
            acc[off] = fmaxf(o[r] + acc[off], 0.0f);
        }
    }
}

// ---------------------------------------------------------------------------
// Full SAGE linear (layer 2): mean = mean @ wl + x @ wr + b, in-place.
// ---------------------------------------------------------------------------
__global__ __launch_bounds__(256) void sage_mm_kernel(
    float* __restrict__ mean, const float* __restrict__ xdst,
    const float* __restrict__ wl, const float* __restrict__ wr,
    const float* __restrict__ bias, int n)
{
    __shared__ float sWl[H * H];
    __shared__ float sWr[H * H];
    __shared__ float sMean[16][H];
    __shared__ float sX[16][H];
    const int col = threadIdx.x & 63;
    const int quad = threadIdx.x >> 6;
    for (int i = threadIdx.x; i < H * H; i += 256) {
        sWl[i] = wl[i];
        sWr[i] = wr[i];
    }
    const int row0 = blockIdx.x * 16;
    for (int r = quad; r < 16; r += 4) {
        int row = row0 + r;
        if (row < n) {
            sMean[r][col] = mean[(size_t)row * H + col];
            sX[r][col]    = xdst[(size_t)row * H + col];
        }
    }
    __syncthreads();

    float o[4];
    o[0] = o[1] = o[2] = o[3] = bias[col];
    #pragma unroll 4
    for (int k = 0; k < H; k += 4) {
        float wl0 = sWl[(k + 0) * H + col], wr0 = sWr[(k + 0) * H + col];
        float wl1 = sWl[(k + 1) * H + col], wr1 = sWr[(k + 1) * H + col];
        float wl2 = sWl[(k + 2) * H + col], wr2 = sWr[(k + 2) * H + col];
        float wl3 = sWl[(k + 3) * H + col], wr3 = sWr[(k + 3) * H + col];
        #pragma unroll
        for (int r = 0; r < 4; ++r) {
            float4 m  = *(const float4*)&sMean[quad + 4 * r][k];
            float4 xx = *(const float4*)&sX[quad + 4 * r][k];
            o[r] += m.x * wl0 + m.y * wl1 + m.z * wl2 + m.w * wl3
                  + xx.x * wr0 + xx.y * wr1 + xx.z * wr2 + xx.w * wr3;
        }
    }
    #pragma unroll
    for (int r = 0; r < 4; ++r) {
        int row = row0 + quad + r * 4;
        if (row < n) mean[(size_t)row * H + col] = o[r];
    }
}

// ---------------------------------------------------------------------------
// Classifier: 2 edges per 16-lane group (4 float4 loads in flight).
// ---------------------------------------------------------------------------
__global__ __launch_bounds__(256) void classify_kernel(
    const float* __restrict__ hg2, const float* __restrict__ hd2,
    const int* __restrict__ ls, const int* __restrict__ ld,
    float* __restrict__ out, int nl)
{
    long long t = (long long)blockIdx.x * blockDim.x + threadIdx.x;
    int grp = (int)(t >> 4);
    int c4 = (int)(t & 15) * 4;
    int e0 = grp * 2;
    if (e0 >= nl) return;
    int e1 = e0 + 1;
    bool has1 = (e1 < nl);
    int a0 = ls[e0], b0 = ld[e0];
    int a1 = has1 ? ls[e1] : a0;
    int b1 = has1 ? ld[e1] : b0;
    float4 va0 = *(const float4*)&hg2[(size_t)a0 * H + c4];
    float4 vb0 = *(const float4*)&hd2[(size_t)b0 * H + c4];
    float4 va1 = *(const float4*)&hg2[(size_t)a1 * H + c4];
    float4 vb1 = *(const float4*)&hd2[(size_t)b1 * H + c4];
    float v0 = va0.x * vb0.x + va0.y * vb0.y + va0.z * vb0.z + va0.w * vb0.w;
    float v1 = va1.x * vb1.x + va1.y * vb1.y + va1.z * vb1.z + va1.w * vb1.w;
    #pragma unroll
    for (int m = 1; m <= 8; m <<= 1) {
        v0 += __shfl_xor(v0, m, 64);
        v1 += __shfl_xor(v1, m, 64);
    }
    if (c4 == 0) {
        out[e0] = v0;
        if (has1) out[e1] = v1;
    }
}

extern "C" void kernel_launch(void* const* d_in, const int* in_sizes, int n_in,
                              void* d_out, int out_size, void* d_ws, size_t ws_size,
                              hipStream_t stream)
{
    const float* gene  = (const float*)d_in[0];
    const float* dis   = (const float*)d_in[1];
    const float* w1gdl = (const float*)d_in[2];
    const float* w1gdr = (const float*)d_in[3];
    const float* w1dgl = (const float*)d_in[4];
    const float* w1dgr = (const float*)d_in[5];
    const float* w2gdl = (const float*)d_in[6];
    const float* w2gdr = (const float*)d_in[7];
    const float* w2dgl = (const float*)d_in[8];
    const float* w2dgr = (const float*)d_in[9];
    const float* b1gd  = (const float*)d_in[10];
    const float* b1dg  = (const float*)d_in[11];
    const float* b2gd  = (const float*)d_in[12];
    const float* b2dg  = (const float*)d_in[13];
    const int* es = (const int*)d_in[14];
    const int* ed = (const int*)d_in[15];
    const int* ls = (const int*)d_in[16];
    const int* ld = (const int*)d_in[17];

    const int ng = in_sizes[0] / H;   // 100000
    const int nd = in_sizes[1] / H;   // 30000
    const int ne = in_sizes[14];      // 1500000
    const int nl = in_sizes[16];      // 500000

    // Workspace layout:
    int* cntD = (int*)d_ws;                            // nd
    int* cntG = cntD + nd;                             // ng
    int* rowD = cntG + ng;                             // nd+1
    int* rowG = rowD + nd + 1;                         // ng+1
    unsigned short* slotD = (unsigned short*)(rowG + ng + 1); // ne
    unsigned short* slotG = slotD + ne;                // ne
    int* idxD = (int*)(slotG + ne);                    // ne
    int* idxG = idxD + ne;                             // ne
    int* partial  = idxG + ne;                         // 1024
    int* blockOff = partial + 1024;                    // 1024
    uintptr_t p = (uintptr_t)(blockOff + 1024);
    p = (p + 15) & ~(uintptr_t)15;
    float* AD = (float*)p;                             // nd*H (self -> h_d)
    float* AG = AD + (size_t)nd * H;                   // ng*H (self -> h_g)
    float* BD = AG + (size_t)ng * H;                   // nd*H (mean -> h_d2)
    float* BG = BD + (size_t)nd * H;                   // ng*H (mean -> h_g2)

    hipMemsetAsync(cntD, 0, (size_t)(nd + ng) * sizeof(int), stream);

    // Fused: histogram+slot recording  ||  layer-1 self halves
    const int HB = (ne + 255) / 256;
    const int MBD = (nd + 15) / 16;
    const int MBG = (ng + 15) / 16;
    fused_hist_selfmm_kernel<<<HB + MBD + MBG, 256, 0, stream>>>(
        es, ed, cntD, cntG, slotD, slotG, ne,
        dis, gene, w1gdr, b1gd, w1dgr, b1dg, AD, AG, nd, ng, HB, MBD);

    // Scan -> row offsets
    const int BD_ = (nd + SCAN_CHUNK - 1) / SCAN_CHUNK;
    const int BG_ = (ng + SCAN_CHUNK - 1) / SCAN_CHUNK;
    const int nbtot = BD_ + BG_;   // must be <= 1024
    scan_reduce_kernel<<<nbtot, 256, 0, stream>>>(cntD, nd, cntG, ng, BD_, partial);
    scan_partials_kernel<<<1, 1024, 0, stream>>>(partial, blockOff, BD_, nbtot,
                                                 rowD, nd, rowG, ng);
    scan_apply_kernel<<<nbtot, 256, 0, stream>>>(cntD, rowD, nd, cntG, rowG, ng,
                                                 BD_, blockOff);

    // Atomic-free banded scatter
    for (int b = 0; b < NBANDS; ++b) {
        int dLo = (int)((long long)nd * b / NBANDS);
        int dHi = (int)((long long)nd * (b + 1) / NBANDS);
        int sLo = (int)((long long)ng * b / NBANDS);
        int sHi = (int)((long long)ng * (b + 1) / NBANDS);
        scatter_band_kernel<<<(ne + 255) / 256, 256, 0, stream>>>(
            es, ed, rowD, rowG, slotD, slotG, idxD, idxG, ne, dLo, dHi, sLo, sHi);
    }

    const int gatherBlocks = (nd + ng + 3) / 4;

    // Layer 1: gather means into B, combine into A (self) with ReLU
    gather_mean_kernel<<<gatherBlocks, 256, 0, stream>>>(
        gene, dis, rowD, idxD, rowG, idxG, BD, BG, nd, ng);
    combine_mm_kernel<<<MBD, 256, 0, stream>>>(AD, BD, w1gdl, nd);
    combine_mm_kernel<<<MBG, 256, 0, stream>>>(AG, BG, w1dgl, ng);

    // Layer 2: gather means of h_g/h_d into B, full linear in-place on B
    gather_mean_kernel<<<gatherBlocks, 256, 0, stream>>>(
        AG, AD, rowD, idxD, rowG, idxG, BD, BG, nd, ng);
    sage_mm_kernel<<<MBD, 256, 0, stream>>>(BD, AD, w2gdl, w2gdr, b2gd, nd);
    sage_mm_kernel<<<MBG, 256, 0, stream>>>(BG, AG, w2dgl, w2dgr, b2dg, ng);

    // Classifier
    {
        long long threads = ((long long)(nl + 1) / 2) * 16;
        int blocks = (int)((threads + 255) / 256);
        classify_kernel<<<blocks, 256, 0, stream>>>(BG, BD, ls, ld,
                                                    (float*)d_out, nl);
    }
}

// Round 5
// 569.970 us; speedup vs baseline: 3.6116x; 1.2422x over previous
//
#include <hip/hip_runtime.h>
#include <hip/hip_bf16.h>

#define H 64
#define SCAN_CHUNK 512
#define NB1 512          // partition blocks (per-(bucket,block) hist = 256*NB1)

// ---------------------------------------------------------------------------
// Partition pass 1: per-block LDS histogram of D-buckets (d>>shiftD) and
// G-buckets (s>>shiftG). No global atomics. histX layout is bucket-major:
// histX[bucket*NB1 + block], so a flat scan gives write cursors directly.
// ---------------------------------------------------------------------------
__global__ __launch_bounds__(256) void part_count_kernel(
    const int* __restrict__ es, const int* __restrict__ ed,
    int* __restrict__ histD, int* __restrict__ histG,
    int ne, int shiftD, int shiftG)
{
    __shared__ int lhd[256], lhg[256];
    const int tid = threadIdx.x;
    lhd[tid] = 0; lhg[tid] = 0;
    __syncthreads();
    const int chunk = (ne + NB1 - 1) / NB1;
    const int e0 = blockIdx.x * chunk;
    const int e1 = min(e0 + chunk, ne);
    for (int e = e0 + tid; e < e1; e += 256) {
        atomicAdd(&lhd[ed[e] >> shiftD], 1);
        atomicAdd(&lhg[es[e] >> shiftG], 1);
    }
    __syncthreads();
    histD[tid * NB1 + blockIdx.x] = lhd[tid];
    histG[tid * NB1 + blockIdx.x] = lhg[tid];
}

// ---------------------------------------------------------------------------
// Scan phase A: per-block reduce of SCAN_CHUNK elements (2 segments).
// ---------------------------------------------------------------------------
__global__ __launch_bounds__(256) void scan_reduce_kernel(
    const int* __restrict__ a1, int n1, const int* __restrict__ a2, int n2,
    int B1, int* __restrict__ partial)
{
    const int b = blockIdx.x;
    const int* a; int n, base;
    if (b < B1) { a = a1; n = n1; base = b * SCAN_CHUNK; }
    else        { a = a2; n = n2; base = (b - B1) * SCAN_CHUNK; }
    int t = threadIdx.x;
    int i0 = base + 2 * t, i1 = i0 + 1;
    int v = ((i0 < n) ? a[i0] : 0) + ((i1 < n) ? a[i1] : 0);
    #pragma unroll
    for (int off = 32; off > 0; off >>= 1) v += __shfl_down(v, off, 64);
    __shared__ int ws[4];
    if ((t & 63) == 0) ws[t >> 6] = v;
    __syncthreads();
    if (t == 0) partial[b] = ws[0] + ws[1] + ws[2] + ws[3];
}

// ---------------------------------------------------------------------------
// Scan phase B: one block scans all partials (<=1024), 2 segments via
// subtract-at-boundary. Also writes out1[n1]=total1, out2[n2]=total2.
// ---------------------------------------------------------------------------
__global__ __launch_bounds__(1024) void scan_partials_kernel(
    const int* __restrict__ partial, int* __restrict__ blockOff,
    int B1, int nbtot,
    int* __restrict__ out1, int n1, int* __restrict__ out2, int n2)
{
    __shared__ int sA[1024], sB[1024];
    int t = threadIdx.x;
    int x = (t < nbtot) ? partial[t] : 0;
    sA[t] = x;
    __syncthreads();
    int* cur = sA; int* nxt = sB;
    for (int off = 1; off < 1024; off <<= 1) {
        int v = cur[t];
        if (t >= off) v += cur[t - off];
        nxt[t] = v;
        __syncthreads();
        int* tmp = cur; cur = nxt; nxt = tmp;
    }
    int incl = cur[t];
    int excl = incl - x;
    int tot1 = cur[B1 - 1];
    if (t < nbtot) blockOff[t] = excl - ((t >= B1) ? tot1 : 0);
    if (t == 0) out1[n1] = tot1;
    if (t == nbtot - 1) out2[n2] = incl - tot1;
}

// ---------------------------------------------------------------------------
// Scan phase C: per-block exclusive scan; writes out[] (the cursors).
// ---------------------------------------------------------------------------
__global__ __launch_bounds__(256) void scan_apply_kernel(
    const int* __restrict__ a1, int* __restrict__ out1, int n1,
    const int* __restrict__ a2, int* __restrict__ out2, int n2,
    int B1, const int* __restrict__ blockOff)
{
    const int b = blockIdx.x;
    const int* a; int* out; int n, base;
    if (b < B1) { a = a1; out = out1; n = n1; base = b * SCAN_CHUNK; }
    else        { a = a2; out = out2; n = n2; base = (b - B1) * SCAN_CHUNK; }
    int t = threadIdx.x;
    int lane = t & 63, wid = t >> 6;
    int i0 = base + 2 * t, i1 = i0 + 1;
    int x0 = (i0 < n) ? a[i0] : 0;
    int x1 = (i1 < n) ? a[i1] : 0;
    int p = x0 + x1;
    int P = p;
    #pragma unroll
    for (int off = 1; off < 64; off <<= 1) {
        int u = __shfl_up(P, off, 64);
        if (lane >= off) P += u;
    }
    __shared__ int ws[4];
    if (lane == 63) ws[wid] = P;
    __syncthreads();
    int waveBase = 0;
    #pragma unroll
    for (int w = 0; w < 4; ++w) waveBase += (w < wid) ? ws[w] : 0;
    int off0 = blockOff[b] + waveBase + (P - p);
    if (i0 < n) out[i0] = off0;
    if (i1 < n) out[i1] = off0 + x0;
}

// ---------------------------------------------------------------------------
// Partition pass 2: re-read chunk, write (key,other) pairs to per-(bucket,
// block) reserved runs. Cursors advanced with LDS atomics only; runs are
// contiguous and L2-resident -> full-line writebacks.
// ---------------------------------------------------------------------------
__global__ __launch_bounds__(256) void part_scatter_kernel(
    const int* __restrict__ es, const int* __restrict__ ed,
    const int* __restrict__ baseD, const int* __restrict__ baseG,
    int2* __restrict__ pairD, int2* __restrict__ pairG,
    int ne, int shiftD, int shiftG)
{
    __shared__ int curD[256], curG[256];
    const int tid = threadIdx.x;
    curD[tid] = baseD[tid * NB1 + blockIdx.x];
    curG[tid] = baseG[tid * NB1 + blockIdx.x];
    __syncthreads();
    const int chunk = (ne + NB1 - 1) / NB1;
    const int e0 = blockIdx.x * chunk;
    const int e1 = min(e0 + chunk, ne);
    for (int e = e0 + tid; e < e1; e += 256) {
        int s = es[e], d = ed[e];
        int pD = atomicAdd(&curD[d >> shiftD], 1);
        pairD[pD] = make_int2(d, s);
        int pG = atomicAdd(&curG[s >> shiftG], 1);
        pairG[pG] = make_int2(s, d);
    }
}

// ---------------------------------------------------------------------------
// CSR finalize: one block per bucket (<=512-node range). LDS histogram of
// keys -> LDS scan -> row[] written directly; second sweep ranks with LDS
// atomics and writes idx[]. No global atomics anywhere.
// Blocks [0,256): D buckets; [256,512): G buckets.
// ---------------------------------------------------------------------------
__global__ __launch_bounds__(256) void csr_build_kernel(
    const int2* __restrict__ pairD, const int* __restrict__ baseD,
    int* __restrict__ rowD, int* __restrict__ idxD, int nd, int shiftD, int nbktD,
    const int2* __restrict__ pairG, const int* __restrict__ baseG,
    int* __restrict__ rowG, int* __restrict__ idxG, int ng, int shiftG, int nbktG)
{
    __shared__ int lcnt[512], lcur[512];
    __shared__ int ws[4];
    const int j = blockIdx.x & 255;
    const int isG = blockIdx.x >> 8;
    const int2* pair; const int* base; int* row; int* idx; int n, shift, nbkt;
    if (isG) { pair = pairG; base = baseG; row = rowG; idx = idxG; n = ng; shift = shiftG; nbkt = nbktG; }
    else     { pair = pairD; base = baseD; row = rowD; idx = idxD; n = nd; shift = shiftD; nbkt = nbktD; }
    if (j >= nbkt) return;

    const int tid = threadIdx.x;
    const int nLo = j << shift;
    const int nHi = min(nLo + (1 << shift), n);
    const int range = nHi - nLo;               // <= 512
    const int segBase = base[j * NB1];
    const int segEnd  = base[(j + 1) * NB1];   // base has n1 extra slot = total

    lcnt[tid] = 0; lcnt[tid + 256] = 0;
    __syncthreads();
    for (int t = segBase + tid; t < segEnd; t += 256)
        atomicAdd(&lcnt[pair[t].x - nLo], 1);
    __syncthreads();

    // exclusive block scan of lcnt[0..range) (2 elems/thread)
    int i0 = 2 * tid, i1 = i0 + 1;
    int c0 = (i0 < range) ? lcnt[i0] : 0;
    int c1 = (i1 < range) ? lcnt[i1] : 0;
    int p = c0 + c1;
    int P = p;
    const int lane = tid & 63, wid = tid >> 6;
    #pragma unroll
    for (int off = 1; off < 64; off <<= 1) {
        int u = __shfl_up(P, off, 64);
        if (lane >= off) P += u;
    }
    if (lane == 63) ws[wid] = P;
    __syncthreads();
    int waveBase = 0;
    #pragma unroll
    for (int w = 0; w < 4; ++w) waveBase += (w < wid) ? ws[w] : 0;
    int o0 = segBase + waveBase + (P - p);
    int o1 = o0 + c0;
    if (i0 < range) { row[nLo + i0] = o0; lcur[i0] = o0; }
    if (i1 < range) { row[nLo + i1] = o1; lcur[i1] = o1; }
    if (nHi == n && tid == 0) row[n] = segEnd;
    __syncthreads();

    for (int t = segBase + tid; t < segEnd; t += 256) {
        int2 pr = pair[t];
        int pos = atomicAdd(&lcur[pr.x - nLo], 1);
        idx[pos] = pr.y;
    }
}

// ---------------------------------------------------------------------------
// Gather-mean for BOTH node sets. Wave per node; quarter-wave float4 layout;
// main loop 16 edges/iter = 4 independent float4 loads in flight.
// ---------------------------------------------------------------------------
__global__ __launch_bounds__(256) void gather_mean_kernel(
    const float* __restrict__ srcD, const float* __restrict__ srcG,
    const int* __restrict__ rowD, const int* __restrict__ idxD,
    const int* __restrict__ rowG, const int* __restrict__ idxG,
    float* __restrict__ outD, float* __restrict__ outG, int nd, int ng)
{
    int w = blockIdx.x * 4 + (threadIdx.x >> 6);
    int lane = threadIdx.x & 63;
    const float* src; const int* row; const int* idx; float* out; int node;
    if (w < nd)            { src = srcD; row = rowD; idx = idxD; out = outD; node = w; }
    else if (w < nd + ng)  { src = srcG; row = rowG; idx = idxG; out = outG; node = w - nd; }
    else return;

    const int sub = lane >> 4;
    const int c4 = (lane & 15) * 4;
    int beg = row[node], end = row[node + 1];

    float4 a0 = make_float4(0.f, 0.f, 0.f, 0.f);
    float4 a1 = make_float4(0.f, 0.f, 0.f, 0.f);
    float4 a2 = make_float4(0.f, 0.f, 0.f, 0.f);
    float4 a3 = make_float4(0.f, 0.f, 0.f, 0.f);
    int i = beg;
    for (; i + 16 <= end; i += 16) {
        int s0 = idx[i + sub];
        int s1 = idx[i + 4 + sub];
        int s2 = idx[i + 8 + sub];
        int s3 = idx[i + 12 + sub];
        float4 v0 = *(const float4*)&src[(size_t)s0 * H + c4];
        float4 v1 = *(const float4*)&src[(size_t)s1 * H + c4];
        float4 v2 = *(const float4*)&src[(size_t)s2 * H + c4];
        float4 v3 = *(const float4*)&src[(size_t)s3 * H + c4];
        a0.x += v0.x; a0.y += v0.y; a0.z += v0.z; a0.w += v0.w;
        a1.x += v1.x; a1.y += v1.y; a1.z += v1.z; a1.w += v1.w;
        a2.x += v2.x; a2.y += v2.y; a2.z += v2.z; a2.w += v2.w;
        a3.x += v3.x; a3.y += v3.y; a3.z += v3.z; a3.w += v3.w;
    }
    if (i + 8 <= end) {
        int s0 = idx[i + sub];
        int s1 = idx[i + 4 + sub];
        float4 v0 = *(const float4*)&src[(size_t)s0 * H + c4];
        float4 v1 = *(const float4*)&src[(size_t)s1 * H + c4];
        a0.x += v0.x; a0.y += v0.y; a0.z += v0.z; a0.w += v0.w;
        a1.x += v1.x; a1.y += v1.y; a1.z += v1.z; a1.w += v1.w;
        i += 8;
    }
    if (i + 4 <= end) {
        int s0 = idx[i + sub];
        float4 v0 = *(const float4*)&src[(size_t)s0 * H + c4];
        a2.x += v0.x; a2.y += v0.y; a2.z += v0.z; a2.w += v0.w;
        i += 4;
    }
    if (i + sub < end) {
        int s1 = idx[i + sub];
        float4 v1 = *(const float4*)&src[(size_t)s1 * H + c4];
        a3.x += v1.x; a3.y += v1.y; a3.z += v1.z; a3.w += v1.w;
    }
    float4 acc = make_float4((a0.x + a1.x) + (a2.x + a3.x),
                             (a0.y + a1.y) + (a2.y + a3.y),
                             (a0.z + a1.z) + (a2.z + a3.z),
                             (a0.w + a1.w) + (a2.w + a3.w));
    #pragma unroll
    for (int m = 16; m <= 32; m <<= 1) {
        acc.x += __shfl_xor(acc.x, m, 64);
        acc.y += __shfl_xor(acc.y, m, 64);
        acc.z += __shfl_xor(acc.z, m, 64);
        acc.w += __shfl_xor(acc.w, m, 64);
    }
    if (sub == 0) {
        float inv = 1.0f / fmaxf((float)(end - beg), 1.0f);
        float4 o = make_float4(acc.x * inv, acc.y * inv, acc.z * inv, acc.w * inv);
        *(float4*)&out[(size_t)node * H + c4] = o;
    }
}

// ---------------------------------------------------------------------------
// SAGE linear: out = act(mean @ wl + x @ wr + b). out may alias mean.
// ---------------------------------------------------------------------------
template <bool RELU>
__global__ __launch_bounds__(256) void sage_mm_kernel(
    const float* mean, const float* __restrict__ xdst, float* out,
    const float* __restrict__ wl, const float* __restrict__ wr,
    const float* __restrict__ bias, int n)
{
    __shared__ float sWl[H * H];
    __shared__ float sWr[H * H];
    __shared__ float sMean[16][H];
    __shared__ float sX[16][H];
    const int col = threadIdx.x & 63;
    const int quad = threadIdx.x >> 6;
    for (int i = threadIdx.x; i < H * H; i += 256) {
        sWl[i] = wl[i];
        sWr[i] = wr[i];
    }
    const int row0 = blockIdx.x * 16;
    for (int r = quad; r < 16; r += 4) {
        int row = row0 + r;
        if (row < n) {
            sMean[r][col] = mean[(size_t)row * H + col];
            sX[r][col]    = xdst[(size_t)row * H + col];
        }
    }
    __syncthreads();

    float o[4];
    o[0] = o[1] = o[2] = o[3] = bias[col];
    #pragma unroll 4
    for (int k = 0; k < H; k += 4) {
        float wl0 = sWl[(k + 0) * H + col], wr0 = sWr[(k + 0) * H + col];
        float wl1 = sWl[(k + 1) * H + col], wr1 = sWr[(k + 1) * H + col];
        float wl2 = sWl[(k + 2) * H + col], wr2 = sWr[(k + 2) * H + col];
        float wl3 = sWl[(k + 3) * H + col], wr3 = sWr[(k + 3) * H + col];
        #pragma unroll
        for (int r = 0; r < 4; ++r) {
            float4 m  = *(const float4*)&sMean[quad + 4 * r][k];
            float4 xx = *(const float4*)&sX[quad + 4 * r][k];
            o[r] += m.x * wl0 + m.y * wl1 + m.z * wl2 + m.w * wl3
                  + xx.x * wr0 + xx.y * wr1 + xx.z * wr2 + xx.w * wr3;
        }
    }
    #pragma unroll
    for (int r = 0; r < 4; ++r) {
        int row = row0 + quad + r * 4;
        if (row < n) {
            float v = o[r];
            if (RELU) v = fmaxf(v, 0.0f);
            out[(size_t)row * H + col] = v;
        }
    }
}

// ---------------------------------------------------------------------------
// Classifier: 2 edges per 16-lane group (4 float4 loads in flight).
// ---------------------------------------------------------------------------
__global__ __launch_bounds__(256) void classify_kernel(
    const float* __restrict__ hg2, const float* __restrict__ hd2,
    const int* __restrict__ ls, const int* __restrict__ ld,
    float* __restrict__ out, int nl)
{
    long long t = (long long)blockIdx.x * blockDim.x + threadIdx.x;
    int grp = (int)(t >> 4);
    int c4 = (int)(t & 15) * 4;
    int e0 = grp * 2;
    if (e0 >= nl) return;
    int e1 = e0 + 1;
    bool has1 = (e1 < nl);
    int a0 = ls[e0], b0 = ld[e0];
    int a1 = has1 ? ls[e1] : a0;
    int b1 = has1 ? ld[e1] : b0;
    float4 va0 = *(const float4*)&hg2[(size_t)a0 * H + c4];
    float4 vb0 = *(const float4*)&hd2[(size_t)b0 * H + c4];
    float4 va1 = *(const float4*)&hg2[(size_t)a1 * H + c4];
    float4 vb1 = *(const float4*)&hd2[(size_t)b1 * H + c4];
    float v0 = va0.x * vb0.x + va0.y * vb0.y + va0.z * vb0.z + va0.w * vb0.w;
    float v1 = va1.x * vb1.x + va1.y * vb1.y + va1.z * vb1.z + va1.w * vb1.w;
    #pragma unroll
    for (int m = 1; m <= 8; m <<= 1) {
        v0 += __shfl_xor(v0, m, 64);
        v1 += __shfl_xor(v1, m, 64);
    }
    if (c4 == 0) {
        out[e0] = v0;
        if (has1) out[e1] = v1;
    }
}

extern "C" void kernel_launch(void* const* d_in, const int* in_sizes, int n_in,
                              void* d_out, int out_size, void* d_ws, size_t ws_size,
                              hipStream_t stream)
{
    const float* gene  = (const float*)d_in[0];
    const float* dis   = (const float*)d_in[1];
    const float* w1gdl = (const float*)d_in[2];
    const float* w1gdr = (const float*)d_in[3];
    const float* w1dgl = (const float*)d_in[4];
    const float* w1dgr = (const float*)d_in[5];
    const float* w2gdl = (const float*)d_in[6];
    const float* w2gdr = (const float*)d_in[7];
    const float* w2dgl = (const float*)d_in[8];
    const float* w2dgr = (const float*)d_in[9];
    const float* b1gd  = (const float*)d_in[10];
    const float* b1dg  = (const float*)d_in[11];
    const float* b2gd  = (const float*)d_in[12];
    const float* b2dg  = (const float*)d_in[13];
    const int* es = (const int*)d_in[14];
    const int* ed = (const int*)d_in[15];
    const int* ls = (const int*)d_in[16];
    const int* ld = (const int*)d_in[17];

    const int ng = in_sizes[0] / H;   // 100000
    const int nd = in_sizes[1] / H;   // 30000
    const int ne = in_sizes[14];      // 1500000
    const int nl = in_sizes[16];      // 500000

    // Bucket shifts: smallest shift giving <= 256 buckets.
    int shiftD = 0; while (((nd + (1 << shiftD) - 1) >> shiftD) > 256) ++shiftD;  // 7
    int shiftG = 0; while (((ng + (1 << shiftG) - 1) >> shiftG) > 256) ++shiftG;  // 9
    const int nbktD = (nd + (1 << shiftD) - 1) >> shiftD;
    const int nbktG = (ng + (1 << shiftG) - 1) >> shiftG;
    const int n1 = 256 * NB1;   // flat hist length per direction

    // Workspace layout (ints unless noted):
    int* histD = (int*)d_ws;             // n1
    int* histG = histD + n1;             // n1
    int* baseD = histG + n1;             // n1 + 1
    int* baseG = baseD + n1 + 1;         // n1 + 1
    int* partial  = baseG + n1 + 1;      // 1024
    int* blockOff = partial + 1024;      // 1024
    int* rowD = blockOff + 1024;         // nd + 1
    int* rowG = rowD + nd + 1;           // ng + 1
    int* idxD = rowG + ng + 1;           // ne
    int* idxG = idxD + ne;               // ne
    uintptr_t p = (uintptr_t)(idxG + ne);
    p = (p + 15) & ~(uintptr_t)15;
    int2* pairD = (int2*)p;              // ne
    int2* pairG = pairD + ne;            // ne
    float* MD = (float*)(pairG + ne);    // nd*H (means; layer-2 output in-place)
    float* MG = MD + (size_t)nd * H;     // ng*H
    float* HD = MG + (size_t)ng * H;     // nd*H (layer-1 h_d)
    float* HG = HD + (size_t)nd * H;     // ng*H (layer-1 h_g)

    // --- CSR build, zero global atomics ---
    part_count_kernel<<<NB1, 256, 0, stream>>>(es, ed, histD, histG,
                                               ne, shiftD, shiftG);
    const int B1 = n1 / SCAN_CHUNK;          // 256
    const int nbtot = 2 * B1;                // 512 <= 1024
    scan_reduce_kernel<<<nbtot, 256, 0, stream>>>(histD, n1, histG, n1, B1, partial);
    scan_partials_kernel<<<1, 1024, 0, stream>>>(partial, blockOff, B1, nbtot,
                                                 baseD, n1, baseG, n1);
    scan_apply_kernel<<<nbtot, 256, 0, stream>>>(histD, baseD, n1,
                                                 histG, baseG, n1, B1, blockOff);
    part_scatter_kernel<<<NB1, 256, 0, stream>>>(es, ed, baseD, baseG,
                                                 pairD, pairG, ne, shiftD, shiftG);
    csr_build_kernel<<<512, 256, 0, stream>>>(
        pairD, baseD, rowD, idxD, nd, shiftD, nbktD,
        pairG, baseG, rowG, idxG, ng, shiftG, nbktG);

    const int gatherBlocks = (nd + ng + 3) / 4;
    const int MBD = (nd + 15) / 16;
    const int MBG = (ng + 15) / 16;

    // Layer 1
    gather_mean_kernel<<<gatherBlocks, 256, 0, stream>>>(
        gene, dis, rowD, idxD, rowG, idxG, MD, MG, nd, ng);
    sage_mm_kernel<true><<<MBD, 256, 0, stream>>>(MD, dis, HD, w1gdl, w1gdr, b1gd, nd);
    sage_mm_kernel<true><<<MBG, 256, 0, stream>>>(MG, gene, HG, w1dgl, w1dgr, b1dg, ng);

    // Layer 2 (means into MD/MG again, linear in-place)
    gather_mean_kernel<<<gatherBlocks, 256, 0, stream>>>(
        HG, HD, rowD, idxD, rowG, idxG, MD, MG, nd, ng);
    sage_mm_kernel<false><<<MBD, 256, 0, stream>>>(MD, HD, MD, w2gdl, w2gdr, b2gd, nd);
    sage_mm_kernel<false><<<MBG, 256, 0, stream>>>(MG, HG, MG, w2dgl, w2dgr, b2dg, ng);

    // Classifier
    {
        long long threads = ((long long)(nl + 1) / 2) * 16;
        int blocks = (int)((threads + 255) / 256);
        classify_kernel<<<blocks, 256, 0, stream>>>(MG, MD, ls, ld,
                                                    (float*)d_out, nl);
    }
}

// Round 6
// 517.593 us; speedup vs baseline: 3.9770x; 1.1012x over previous
//
#include <hip/hip_runtime.h>
#include <hip/hip_bf16.h>

#define H 64
#define SCAN_CHUNK 512
#define NB1 512          // partition blocks (per-(bucket,block) hist = 256*NB1)

typedef unsigned short u16;
typedef unsigned int u32;

__device__ __forceinline__ float bflo(u32 u) {
    return __builtin_bit_cast(float, u << 16);
}
__device__ __forceinline__ float bfhi(u32 u) {
    return __builtin_bit_cast(float, u & 0xffff0000u);
}
__device__ __forceinline__ u16 bf16rne(float f) {
    u32 u = __builtin_bit_cast(u32, f);
    return (u16)((u + 0x7FFFu + ((u >> 16) & 1u)) >> 16);
}
__device__ __forceinline__ float bfu(u16 v) {
    return __builtin_bit_cast(float, (u32)v << 16);
}

// ---------------------------------------------------------------------------
// fp32 -> bf16 (RNE) conversion for the two embedding tables, 4 elems/thread.
// ---------------------------------------------------------------------------
__global__ __launch_bounds__(256) void convert_bf16_kernel(
    const float* __restrict__ a, u16* __restrict__ oa, long long na4,
    const float* __restrict__ b, u16* __restrict__ ob, long long nb4)
{
    long long i = (long long)blockIdx.x * blockDim.x + threadIdx.x;
    const float* src; u16* dst; long long q;
    if (i < na4) { src = a; dst = oa; q = i; }
    else if (i < na4 + nb4) { src = b; dst = ob; q = i - na4; }
    else return;
    float4 v = *(const float4*)&src[q * 4];
    ushort4 o;
    o.x = bf16rne(v.x); o.y = bf16rne(v.y);
    o.z = bf16rne(v.z); o.w = bf16rne(v.w);
    *(ushort4*)&dst[q * 4] = o;
}

// ---------------------------------------------------------------------------
// Partition pass 1: per-block LDS histogram of D-buckets (d>>shiftD) and
// G-buckets (s>>shiftG). No global atomics. Bucket-major layout.
// ---------------------------------------------------------------------------
__global__ __launch_bounds__(256) void part_count_kernel(
    const int* __restrict__ es, const int* __restrict__ ed,
    int* __restrict__ histD, int* __restrict__ histG,
    int ne, int shiftD, int shiftG)
{
    __shared__ int lhd[256], lhg[256];
    const int tid = threadIdx.x;
    lhd[tid] = 0; lhg[tid] = 0;
    __syncthreads();
    const int chunk = (ne + NB1 - 1) / NB1;
    const int e0 = blockIdx.x * chunk;
    const int e1 = min(e0 + chunk, ne);
    for (int e = e0 + tid; e < e1; e += 256) {
        atomicAdd(&lhd[ed[e] >> shiftD], 1);
        atomicAdd(&lhg[es[e] >> shiftG], 1);
    }
    __syncthreads();
    histD[tid * NB1 + blockIdx.x] = lhd[tid];
    histG[tid * NB1 + blockIdx.x] = lhg[tid];
}

// ---------------------------------------------------------------------------
// Scan phase A: per-block reduce of SCAN_CHUNK elements (2 segments).
// ---------------------------------------------------------------------------
__global__ __launch_bounds__(256) void scan_reduce_kernel(
    const int* __restrict__ a1, int n1, const int* __restrict__ a2, int n2,
    int B1, int* __restrict__ partial)
{
    const int b = blockIdx.x;
    const int* a; int n, base;
    if (b < B1) { a = a1; n = n1; base = b * SCAN_CHUNK; }
    else        { a = a2; n = n2; base = (b - B1) * SCAN_CHUNK; }
    int t = threadIdx.x;
    int i0 = base + 2 * t, i1 = i0 + 1;
    int v = ((i0 < n) ? a[i0] : 0) + ((i1 < n) ? a[i1] : 0);
    #pragma unroll
    for (int off = 32; off > 0; off >>= 1) v += __shfl_down(v, off, 64);
    __shared__ int ws[4];
    if ((t & 63) == 0) ws[t >> 6] = v;
    __syncthreads();
    if (t == 0) partial[b] = ws[0] + ws[1] + ws[2] + ws[3];
}

// ---------------------------------------------------------------------------
// Scan phase B: one block scans all partials (<=1024), 2 segments.
// ---------------------------------------------------------------------------
__global__ __launch_bounds__(1024) void scan_partials_kernel(
    const int* __restrict__ partial, int* __restrict__ blockOff,
    int B1, int nbtot,
    int* __restrict__ out1, int n1, int* __restrict__ out2, int n2)
{
    __shared__ int sA[1024], sB[1024];
    int t = threadIdx.x;
    int x = (t < nbtot) ? partial[t] : 0;
    sA[t] = x;
    __syncthreads();
    int* cur = sA; int* nxt = sB;
    for (int off = 1; off < 1024; off <<= 1) {
        int v = cur[t];
        if (t >= off) v += cur[t - off];
        nxt[t] = v;
        __syncthreads();
        int* tmp = cur; cur = nxt; nxt = tmp;
    }
    int incl = cur[t];
    int excl = incl - x;
    int tot1 = cur[B1 - 1];
    if (t < nbtot) blockOff[t] = excl - ((t >= B1) ? tot1 : 0);
    if (t == 0) out1[n1] = tot1;
    if (t == nbtot - 1) out2[n2] = incl - tot1;
}

// ---------------------------------------------------------------------------
// Scan phase C: per-block exclusive scan; writes cursor arrays.
// ---------------------------------------------------------------------------
__global__ __launch_bounds__(256) void scan_apply_kernel(
    const int* __restrict__ a1, int* __restrict__ out1, int n1,
    const int* __restrict__ a2, int* __restrict__ out2, int n2,
    int B1, const int* __restrict__ blockOff)
{
    const int b = blockIdx.x;
    const int* a; int* out; int n, base;
    if (b < B1) { a = a1; out = out1; n = n1; base = b * SCAN_CHUNK; }
    else        { a = a2; out = out2; n = n2; base = (b - B1) * SCAN_CHUNK; }
    int t = threadIdx.x;
    int lane = t & 63, wid = t >> 6;
    int i0 = base + 2 * t, i1 = i0 + 1;
    int x0 = (i0 < n) ? a[i0] : 0;
    int x1 = (i1 < n) ? a[i1] : 0;
    int p = x0 + x1;
    int P = p;
    #pragma unroll
    for (int off = 1; off < 64; off <<= 1) {
        int u = __shfl_up(P, off, 64);
        if (lane >= off) P += u;
    }
    __shared__ int ws[4];
    if (lane == 63) ws[wid] = P;
    __syncthreads();
    int waveBase = 0;
    #pragma unroll
    for (int w = 0; w < 4; ++w) waveBase += (w < wid) ? ws[w] : 0;
    int off0 = blockOff[b] + waveBase + (P - p);
    if (i0 < n) out[i0] = off0;
    if (i1 < n) out[i1] = off0 + x0;
}

// ---------------------------------------------------------------------------
// Partition pass 2: write (key,other) pairs to per-(bucket,block) runs.
// LDS-atomic cursors only; runs contiguous & L2-resident.
// ---------------------------------------------------------------------------
__global__ __launch_bounds__(256) void part_scatter_kernel(
    const int* __restrict__ es, const int* __restrict__ ed,
    const int* __restrict__ baseD, const int* __restrict__ baseG,
    int2* __restrict__ pairD, int2* __restrict__ pairG,
    int ne, int shiftD, int shiftG)
{
    __shared__ int curD[256], curG[256];
    const int tid = threadIdx.x;
    curD[tid] = baseD[tid * NB1 + blockIdx.x];
    curG[tid] = baseG[tid * NB1 + blockIdx.x];
    __syncthreads();
    const int chunk = (ne + NB1 - 1) / NB1;
    const int e0 = blockIdx.x * chunk;
    const int e1 = min(e0 + chunk, ne);
    for (int e = e0 + tid; e < e1; e += 256) {
        int s = es[e], d = ed[e];
        int pD = atomicAdd(&curD[d >> shiftD], 1);
        pairD[pD] = make_int2(d, s);
        int pG = atomicAdd(&curG[s >> shiftG], 1);
        pairG[pG] = make_int2(s, d);
    }
}

// ---------------------------------------------------------------------------
// CSR finalize: one block per bucket. LDS hist -> LDS scan -> row[]; second
// sweep ranks with LDS atomics, writes idx[]. No global atomics.
// ---------------------------------------------------------------------------
__global__ __launch_bounds__(256) void csr_build_kernel(
    const int2* __restrict__ pairD, const int* __restrict__ baseD,
    int* __restrict__ rowD, int* __restrict__ idxD, int nd, int shiftD, int nbktD,
    const int2* __restrict__ pairG, const int* __restrict__ baseG,
    int* __restrict__ rowG, int* __restrict__ idxG, int ng, int shiftG, int nbktG)
{
    __shared__ int lcnt[512], lcur[512];
    __shared__ int ws[4];
    const int j = blockIdx.x & 255;
    const int isG = blockIdx.x >> 8;
    const int2* pair; const int* base; int* row; int* idx; int n, shift, nbkt;
    if (isG) { pair = pairG; base = baseG; row = rowG; idx = idxG; n = ng; shift = shiftG; nbkt = nbktG; }
    else     { pair = pairD; base = baseD; row = rowD; idx = idxD; n = nd; shift = shiftD; nbkt = nbktD; }
    if (j >= nbkt) return;

    const int tid = threadIdx.x;
    const int nLo = j << shift;
    const int nHi = min(nLo + (1 << shift), n);
    const int range = nHi - nLo;               // <= 512
    const int segBase = base[j * NB1];
    const int segEnd  = base[(j + 1) * NB1];

    lcnt[tid] = 0; lcnt[tid + 256] = 0;
    __syncthreads();
    for (int t = segBase + tid; t < segEnd; t += 256)
        atomicAdd(&lcnt[pair[t].x - nLo], 1);
    __syncthreads();

    int i0 = 2 * tid, i1 = i0 + 1;
    int c0 = (i0 < range) ? lcnt[i0] : 0;
    int c1 = (i1 < range) ? lcnt[i1] : 0;
    int p = c0 + c1;
    int P = p;
    const int lane = tid & 63, wid = tid >> 6;
    #pragma unroll
    for (int off = 1; off < 64; off <<= 1) {
        int u = __shfl_up(P, off, 64);
        if (lane >= off) P += u;
    }
    if (lane == 63) ws[wid] = P;
    __syncthreads();
    int waveBase = 0;
    #pragma unroll
    for (int w = 0; w < 4; ++w) waveBase += (w < wid) ? ws[w] : 0;
    int o0 = segBase + waveBase + (P - p);
    int o1 = o0 + c0;
    if (i0 < range) { row[nLo + i0] = o0; lcur[i0] = o0; }
    if (i1 < range) { row[nLo + i1] = o1; lcur[i1] = o1; }
    if (nHi == n && tid == 0) row[n] = segEnd;
    __syncthreads();

    for (int t = segBase + tid; t < segEnd; t += 256) {
        int2 pr = pair[t];
        int pos = atomicAdd(&lcur[pr.x - nLo], 1);
        idx[pos] = pr.y;
    }
}

// ---------------------------------------------------------------------------
// Gather-mean over bf16 source rows (128 B/row). Wave per node; quarter-wave
// layout: lane=16*sub+c4, lane loads uint2 = 4 bf16 channels of edge i+sub.
// 16 edges/iter = 4 independent 8 B loads in flight. fp32 accumulate/output.
// ---------------------------------------------------------------------------
__global__ __launch_bounds__(256) void gather_mean_kernel(
    const u16* __restrict__ srcD, const u16* __restrict__ srcG,
    const int* __restrict__ rowD, const int* __restrict__ idxD,
    const int* __restrict__ rowG, const int* __restrict__ idxG,
    float* __restrict__ outD, float* __restrict__ outG, int nd, int ng)
{
    int w = blockIdx.x * 4 + (threadIdx.x >> 6);
    int lane = threadIdx.x & 63;
    const u16* src; const int* row; const int* idx; float* out; int node;
    if (w < nd)            { src = srcD; row = rowD; idx = idxD; out = outD; node = w; }
    else if (w < nd + ng)  { src = srcG; row = rowG; idx = idxG; out = outG; node = w - nd; }
    else return;

    const int sub = lane >> 4;
    const int c4 = lane & 15;       // uint2 index within row (4 bf16 per uint2)
    int beg = row[node], end = row[node + 1];

    float4 a0 = make_float4(0.f, 0.f, 0.f, 0.f);
    float4 a1 = make_float4(0.f, 0.f, 0.f, 0.f);
    float4 a2 = make_float4(0.f, 0.f, 0.f, 0.f);
    float4 a3 = make_float4(0.f, 0.f, 0.f, 0.f);
    int i = beg;
    for (; i + 16 <= end; i += 16) {
        int s0 = idx[i + sub];
        int s1 = idx[i + 4 + sub];
        int s2 = idx[i + 8 + sub];
        int s3 = idx[i + 12 + sub];
        uint2 v0 = *((const uint2*)(src + (size_t)s0 * H) + c4);
        uint2 v1 = *((const uint2*)(src + (size_t)s1 * H) + c4);
        uint2 v2 = *((const uint2*)(src + (size_t)s2 * H) + c4);
        uint2 v3 = *((const uint2*)(src + (size_t)s3 * H) + c4);
        a0.x += bflo(v0.x); a0.y += bfhi(v0.x); a0.z += bflo(v0.y); a0.w += bfhi(v0.y);
        a1.x += bflo(v1.x); a1.y += bfhi(v1.x); a1.z += bflo(v1.y); a1.w += bfhi(v1.y);
        a2.x += bflo(v2.x); a2.y += bfhi(v2.x); a2.z += bflo(v2.y); a2.w += bfhi(v2.y);
        a3.x += bflo(v3.x); a3.y += bfhi(v3.x); a3.z += bflo(v3.y); a3.w += bfhi(v3.y);
    }
    if (i + 8 <= end) {
        int s0 = idx[i + sub];
        int s1 = idx[i + 4 + sub];
        uint2 v0 = *((const uint2*)(src + (size_t)s0 * H) + c4);
        uint2 v1 = *((const uint2*)(src + (size_t)s1 * H) + c4);
        a0.x += bflo(v0.x); a0.y += bfhi(v0.x); a0.z += bflo(v0.y); a0.w += bfhi(v0.y);
        a1.x += bflo(v1.x); a1.y += bfhi(v1.x); a1.z += bflo(v1.y); a1.w += bfhi(v1.y);
        i += 8;
    }
    if (i + 4 <= end) {
        int s0 = idx[i + sub];
        uint2 v0 = *((const uint2*)(src + (size_t)s0 * H) + c4);
        a2.x += bflo(v0.x); a2.y += bfhi(v0.x); a2.z += bflo(v0.y); a2.w += bfhi(v0.y);
        i += 4;
    }
    if (i + sub < end) {
        int s1 = idx[i + sub];
        uint2 v1 = *((const uint2*)(src + (size_t)s1 * H) + c4);
        a3.x += bflo(v1.x); a3.y += bfhi(v1.x); a3.z += bflo(v1.y); a3.w += bfhi(v1.y);
    }
    float4 acc = make_float4((a0.x + a1.x) + (a2.x + a3.x),
                             (a0.y + a1.y) + (a2.y + a3.y),
                             (a0.z + a1.z) + (a2.z + a3.z),
                             (a0.w + a1.w) + (a2.w + a3.w));
    #pragma unroll
    for (int m = 16; m <= 32; m <<= 1) {
        acc.x += __shfl_xor(acc.x, m, 64);
        acc.y += __shfl_xor(acc.y, m, 64);
        acc.z += __shfl_xor(acc.z, m, 64);
        acc.w += __shfl_xor(acc.w, m, 64);
    }
    if (sub == 0) {
        float inv = 1.0f / fmaxf((float)(end - beg), 1.0f);
        float4 o = make_float4(acc.x * inv, acc.y * inv, acc.z * inv, acc.w * inv);
        *(float4*)&out[(size_t)node * H + c4 * 4] = o;
    }
}

// ---------------------------------------------------------------------------
// SAGE linear: out_bf16 = act(mean @ wl + x @ wr + b).
// mean fp32; x is fp32 (layer 1: original tables) or bf16 (layer 2: h1).
// ---------------------------------------------------------------------------
template <bool RELU, bool XBF16>
__global__ __launch_bounds__(256) void sage_mm_kernel(
    const float* __restrict__ mean, const void* __restrict__ xdst,
    u16* __restrict__ outBf,
    const float* __restrict__ wl, const float* __restrict__ wr,
    const float* __restrict__ bias, int n)
{
    __shared__ float sWl[H * H];
    __shared__ float sWr[H * H];
    __shared__ float sMean[16][H];
    __shared__ float sX[16][H];
    const int col = threadIdx.x & 63;
    const int quad = threadIdx.x >> 6;
    for (int i = threadIdx.x; i < H * H; i += 256) {
        sWl[i] = wl[i];
        sWr[i] = wr[i];
    }
    const int row0 = blockIdx.x * 16;
    for (int r = quad; r < 16; r += 4) {
        int row = row0 + r;
        if (row < n) {
            sMean[r][col] = mean[(size_t)row * H + col];
            if (XBF16) {
                const u16* xb = (const u16*)xdst;
                sX[r][col] = bfu(xb[(size_t)row * H + col]);
            } else {
                const float* xf = (const float*)xdst;
                sX[r][col] = xf[(size_t)row * H + col];
            }
        }
    }
    __syncthreads();

    float o[4];
    o[0] = o[1] = o[2] = o[3] = bias[col];
    #pragma unroll 4
    for (int k = 0; k < H; k += 4) {
        float wl0 = sWl[(k + 0) * H + col], wr0 = sWr[(k + 0) * H + col];
        float wl1 = sWl[(k + 1) * H + col], wr1 = sWr[(k + 1) * H + col];
        float wl2 = sWl[(k + 2) * H + col], wr2 = sWr[(k + 2) * H + col];
        float wl3 = sWl[(k + 3) * H + col], wr3 = sWr[(k + 3) * H + col];
        #pragma unroll
        for (int r = 0; r < 4; ++r) {
            float4 m  = *(const float4*)&sMean[quad + 4 * r][k];
            float4 xx = *(const float4*)&sX[quad + 4 * r][k];
            o[r] += m.x * wl0 + m.y * wl1 + m.z * wl2 + m.w * wl3
                  + xx.x * wr0 + xx.y * wr1 + xx.z * wr2 + xx.w * wr3;
        }
    }
    #pragma unroll
    for (int r = 0; r < 4; ++r) {
        int row = row0 + quad + r * 4;
        if (row < n) {
            float v = o[r];
            if (RELU) v = fmaxf(v, 0.0f);
            outBf[(size_t)row * H + col] = bf16rne(v);
        }
    }
}

// ---------------------------------------------------------------------------
// Classifier on bf16 rows: 2 edges per 16-lane group, uint2 loads, fp32 dot.
// ---------------------------------------------------------------------------
__global__ __launch_bounds__(256) void classify_kernel(
    const u16* __restrict__ hg2, const u16* __restrict__ hd2,
    const int* __restrict__ ls, const int* __restrict__ ld,
    float* __restrict__ out, int nl)
{
    long long t = (long long)blockIdx.x * blockDim.x + threadIdx.x;
    int grp = (int)(t >> 4);
    int c4 = (int)(t & 15);
    int e0 = grp * 2;
    if (e0 >= nl) return;
    int e1 = e0 + 1;
    bool has1 = (e1 < nl);
    int a0 = ls[e0], b0 = ld[e0];
    int a1 = has1 ? ls[e1] : a0;
    int b1 = has1 ? ld[e1] : b0;
    uint2 ua0 = *((const uint2*)(hg2 + (size_t)a0 * H) + c4);
    uint2 ub0 = *((const uint2*)(hd2 + (size_t)b0 * H) + c4);
    uint2 ua1 = *((const uint2*)(hg2 + (size_t)a1 * H) + c4);
    uint2 ub1 = *((const uint2*)(hd2 + (size_t)b1 * H) + c4);
    float v0 = bflo(ua0.x) * bflo(ub0.x) + bfhi(ua0.x) * bfhi(ub0.x)
             + bflo(ua0.y) * bflo(ub0.y) + bfhi(ua0.y) * bfhi(ub0.y);
    float v1 = bflo(ua1.x) * bflo(ub1.x) + bfhi(ua1.x) * bfhi(ub1.x)
             + bflo(ua1.y) * bflo(ub1.y) + bfhi(ua1.y) * bfhi(ub1.y);
    #pragma unroll
    for (int m = 1; m <= 8; m <<= 1) {
        v0 += __shfl_xor(v0, m, 64);
        v1 += __shfl_xor(v1, m, 64);
    }
    if (c4 == 0) {
        out[e0] = v0;
        if (has1) out[e1] = v1;
    }
}

extern "C" void kernel_launch(void* const* d_in, const int* in_sizes, int n_in,
                              void* d_out, int out_size, void* d_ws, size_t ws_size,
                              hipStream_t stream)
{
    const float* gene  = (const float*)d_in[0];
    const float* dis   = (const float*)d_in[1];
    const float* w1gdl = (const float*)d_in[2];
    const float* w1gdr = (const float*)d_in[3];
    const float* w1dgl = (const float*)d_in[4];
    const float* w1dgr = (const float*)d_in[5];
    const float* w2gdl = (const float*)d_in[6];
    const float* w2gdr = (const float*)d_in[7];
    const float* w2dgl = (const float*)d_in[8];
    const float* w2dgr = (const float*)d_in[9];
    const float* b1gd  = (const float*)d_in[10];
    const float* b1dg  = (const float*)d_in[11];
    const float* b2gd  = (const float*)d_in[12];
    const float* b2dg  = (const float*)d_in[13];
    const int* es = (const int*)d_in[14];
    const int* ed = (const int*)d_in[15];
    const int* ls = (const int*)d_in[16];
    const int* ld = (const int*)d_in[17];

    const int ng = in_sizes[0] / H;   // 100000
    const int nd = in_sizes[1] / H;   // 30000
    const int ne = in_sizes[14];      // 1500000
    const int nl = in_sizes[16];      // 500000

    int shiftD = 0; while (((nd + (1 << shiftD) - 1) >> shiftD) > 256) ++shiftD;  // 7
    int shiftG = 0; while (((ng + (1 << shiftG) - 1) >> shiftG) > 256) ++shiftG;  // 9
    const int nbktD = (nd + (1 << shiftD) - 1) >> shiftD;
    const int nbktG = (ng + (1 << shiftG) - 1) >> shiftG;
    const int n1 = 256 * NB1;

    // --- Workspace layout ---
    // Persistent: CSR (row/idx), bf16 tables, bf16 h1/h2.
    int* rowD = (int*)d_ws;                         // nd+1
    int* rowG = rowD + nd + 1;                      // ng+1
    int* idxD = rowG + ng + 1;                      // ne
    int* idxG = idxD + ne;                          // ne
    u16* geneBf = (u16*)(idxG + ne);                // ng*H
    u16* disBf  = geneBf + (size_t)ng * H;          // nd*H
    u16* h1Dbf  = disBf + (size_t)nd * H;           // nd*H
    u16* h1Gbf  = h1Dbf + (size_t)nd * H;           // ng*H
    u16* h2Dbf  = h1Gbf + (size_t)ng * H;           // nd*H
    u16* h2Gbf  = h2Dbf + (size_t)nd * H;           // ng*H
    uintptr_t p = (uintptr_t)(h2Gbf + (size_t)ng * H);
    p = (p + 15) & ~(uintptr_t)15;
    // Union region: CSR-build scratch (dead after csr_build) aliased with means.
    float* MD = (float*)p;                          // nd*H
    float* MG = MD + (size_t)nd * H;                // ng*H
    int* histD = (int*)p;                           // n1
    int* histG = histD + n1;                        // n1
    int* baseD = histG + n1;                        // n1+1
    int* baseG = baseD + n1 + 1;                    // n1+1
    int* partial  = baseG + n1 + 1;                 // 1024
    int* blockOff = partial + 1024;                 // 1024
    uintptr_t pp = (uintptr_t)(blockOff + 1024);
    pp = (pp + 15) & ~(uintptr_t)15;
    int2* pairD = (int2*)pp;                        // ne
    int2* pairG = pairD + ne;                       // ne
    // NOTE: means region (33.3 MB) covers scratch (~32.3 MB); means are first
    // written by gather1, which runs strictly after csr_build.

    // --- bf16 conversion of embedding tables ---
    {
        long long na4 = (long long)ng * H / 4;
        long long nb4 = (long long)nd * H / 4;
        long long tot = na4 + nb4;
        int blocks = (int)((tot + 255) / 256);
        convert_bf16_kernel<<<blocks, 256, 0, stream>>>(gene, geneBf, na4,
                                                        dis, disBf, nb4);
    }

    // --- CSR build, zero global atomics ---
    part_count_kernel<<<NB1, 256, 0, stream>>>(es, ed, histD, histG,
                                               ne, shiftD, shiftG);
    const int B1 = n1 / SCAN_CHUNK;          // 256
    const int nbtot = 2 * B1;                // 512
    scan_reduce_kernel<<<nbtot, 256, 0, stream>>>(histD, n1, histG, n1, B1, partial);
    scan_partials_kernel<<<1, 1024, 0, stream>>>(partial, blockOff, B1, nbtot,
                                                 baseD, n1, baseG, n1);
    scan_apply_kernel<<<nbtot, 256, 0, stream>>>(histD, baseD, n1,
                                                 histG, baseG, n1, B1, blockOff);
    part_scatter_kernel<<<NB1, 256, 0, stream>>>(es, ed, baseD, baseG,
                                                 pairD, pairG, ne, shiftD, shiftG);
    csr_build_kernel<<<512, 256, 0, stream>>>(
        pairD, baseD, rowD, idxD, nd, shiftD, nbktD,
        pairG, baseG, rowG, idxG, ng, shiftG, nbktG);

    const int gatherBlocks = (nd + ng + 3) / 4;
    const int MBD = (nd + 15) / 16;
    const int MBG = (ng + 15) / 16;

    // Layer 1: bf16 gathers -> fp32 means; mm with fp32 x -> bf16 h1
    gather_mean_kernel<<<gatherBlocks, 256, 0, stream>>>(
        geneBf, disBf, rowD, idxD, rowG, idxG, MD, MG, nd, ng);
    sage_mm_kernel<true, false><<<MBD, 256, 0, stream>>>(
        MD, dis, h1Dbf, w1gdl, w1gdr, b1gd, nd);
    sage_mm_kernel<true, false><<<MBG, 256, 0, stream>>>(
        MG, gene, h1Gbf, w1dgl, w1dgr, b1dg, ng);

    // Layer 2: gathers over bf16 h1; mm with bf16 x -> bf16 h2
    gather_mean_kernel<<<gatherBlocks, 256, 0, stream>>>(
        h1Gbf, h1Dbf, rowD, idxD, rowG, idxG, MD, MG, nd, ng);
    sage_mm_kernel<false, true><<<MBD, 256, 0, stream>>>(
        MD, h1Dbf, h2Dbf, w2gdl, w2gdr, b2gd, nd);
    sage_mm_kernel<false, true><<<MBG, 256, 0, stream>>>(
        MG, h1Gbf, h2Gbf, w2dgl, w2dgr, b2dg, ng);

    // Classifier on bf16 h2
    {
        long long threads = ((long long)(nl + 1) / 2) * 16;
        int blocks = (int)((threads + 255) / 256);
        classify_kernel<<<blocks, 256, 0, stream>>>(h2Gbf, h2Dbf, ls, ld,
                                                    (float*)d_out, nl);
    }
}

// Round 7
// 485.334 us; speedup vs baseline: 4.2414x; 1.0665x over previous
//
#include <hip/hip_runtime.h>
#include <hip/hip_bf16.h>

#define H 64
#define SCAN_CHUNK 512
#define NB1 512          // partition blocks (per-(bucket,block) hist = 256*NB1)

typedef unsigned short u16;
typedef unsigned int u32;

__device__ __forceinline__ float bflo(u32 u) {
    return __builtin_bit_cast(float, u << 16);
}
__device__ __forceinline__ float bfhi(u32 u) {
    return __builtin_bit_cast(float, u & 0xffff0000u);
}
__device__ __forceinline__ u16 bf16rne(float f) {
    u32 u = __builtin_bit_cast(u32, f);
    return (u16)((u + 0x7FFFu + ((u >> 16) & 1u)) >> 16);
}
__device__ __forceinline__ float bfu(u16 v) {
    return __builtin_bit_cast(float, (u32)v << 16);
}

// ---------------------------------------------------------------------------
// Fused: blocks [0,NB1) = partition histogram (LDS atomics, bucket-major out);
// blocks [NB1,...) = fp32->bf16 table conversion (pure BW, rides along).
// ---------------------------------------------------------------------------
__global__ __launch_bounds__(256) void fused_count_convert_kernel(
    const int* __restrict__ es, const int* __restrict__ ed,
    int* __restrict__ histD, int* __restrict__ histG,
    int ne, int shiftD, int shiftG,
    const float* __restrict__ a, u16* __restrict__ oa, long long na4,
    const float* __restrict__ b, u16* __restrict__ ob, long long nb4)
{
    if (blockIdx.x < NB1) {
        __shared__ int lhd[256], lhg[256];
        const int tid = threadIdx.x;
        lhd[tid] = 0; lhg[tid] = 0;
        __syncthreads();
        const int chunk = (ne + NB1 - 1) / NB1;
        const int e0 = blockIdx.x * chunk;
        const int e1 = min(e0 + chunk, ne);
        for (int e = e0 + tid; e < e1; e += 256) {
            atomicAdd(&lhd[ed[e] >> shiftD], 1);
            atomicAdd(&lhg[es[e] >> shiftG], 1);
        }
        __syncthreads();
        histD[tid * NB1 + blockIdx.x] = lhd[tid];
        histG[tid * NB1 + blockIdx.x] = lhg[tid];
        return;
    }
    long long i = (long long)(blockIdx.x - NB1) * 256 + threadIdx.x;
    const float* src; u16* dst; long long q;
    if (i < na4) { src = a; dst = oa; q = i; }
    else if (i < na4 + nb4) { src = b; dst = ob; q = i - na4; }
    else return;
    float4 v = *(const float4*)&src[q * 4];
    ushort4 o;
    o.x = bf16rne(v.x); o.y = bf16rne(v.y);
    o.z = bf16rne(v.z); o.w = bf16rne(v.w);
    *(ushort4*)&dst[q * 4] = o;
}

// ---------------------------------------------------------------------------
// Scan phase A: per-block reduce of SCAN_CHUNK elements (2 segments).
// ---------------------------------------------------------------------------
__global__ __launch_bounds__(256) void scan_reduce_kernel(
    const int* __restrict__ a1, int n1, const int* __restrict__ a2, int n2,
    int B1, int* __restrict__ partial)
{
    const int b = blockIdx.x;
    const int* a; int n, base;
    if (b < B1) { a = a1; n = n1; base = b * SCAN_CHUNK; }
    else        { a = a2; n = n2; base = (b - B1) * SCAN_CHUNK; }
    int t = threadIdx.x;
    int i0 = base + 2 * t, i1 = i0 + 1;
    int v = ((i0 < n) ? a[i0] : 0) + ((i1 < n) ? a[i1] : 0);
    #pragma unroll
    for (int off = 32; off > 0; off >>= 1) v += __shfl_down(v, off, 64);
    __shared__ int ws[4];
    if ((t & 63) == 0) ws[t >> 6] = v;
    __syncthreads();
    if (t == 0) partial[b] = ws[0] + ws[1] + ws[2] + ws[3];
}

// ---------------------------------------------------------------------------
// Scan phase B: one block scans all partials (<=1024), 2 segments.
// ---------------------------------------------------------------------------
__global__ __launch_bounds__(1024) void scan_partials_kernel(
    const int* __restrict__ partial, int* __restrict__ blockOff,
    int B1, int nbtot,
    int* __restrict__ out1, int n1, int* __restrict__ out2, int n2)
{
    __shared__ int sA[1024], sB[1024];
    int t = threadIdx.x;
    int x = (t < nbtot) ? partial[t] : 0;
    sA[t] = x;
    __syncthreads();
    int* cur = sA; int* nxt = sB;
    for (int off = 1; off < 1024; off <<= 1) {
        int v = cur[t];
        if (t >= off) v += cur[t - off];
        nxt[t] = v;
        __syncthreads();
        int* tmp = cur; cur = nxt; nxt = tmp;
    }
    int incl = cur[t];
    int excl = incl - x;
    int tot1 = cur[B1 - 1];
    if (t < nbtot) blockOff[t] = excl - ((t >= B1) ? tot1 : 0);
    if (t == 0) out1[n1] = tot1;
    if (t == nbtot - 1) out2[n2] = incl - tot1;
}

// ---------------------------------------------------------------------------
// Scan phase C: per-block exclusive scan; writes cursor arrays.
// ---------------------------------------------------------------------------
__global__ __launch_bounds__(256) void scan_apply_kernel(
    const int* __restrict__ a1, int* __restrict__ out1, int n1,
    const int* __restrict__ a2, int* __restrict__ out2, int n2,
    int B1, const int* __restrict__ blockOff)
{
    const int b = blockIdx.x;
    const int* a; int* out; int n, base;
    if (b < B1) { a = a1; out = out1; n = n1; base = b * SCAN_CHUNK; }
    else        { a = a2; out = out2; n = n2; base = (b - B1) * SCAN_CHUNK; }
    int t = threadIdx.x;
    int lane = t & 63, wid = t >> 6;
    int i0 = base + 2 * t, i1 = i0 + 1;
    int x0 = (i0 < n) ? a[i0] : 0;
    int x1 = (i1 < n) ? a[i1] : 0;
    int p = x0 + x1;
    int P = p;
    #pragma unroll
    for (int off = 1; off < 64; off <<= 1) {
        int u = __shfl_up(P, off, 64);
        if (lane >= off) P += u;
    }
    __shared__ int ws[4];
    if (lane == 63) ws[wid] = P;
    __syncthreads();
    int waveBase = 0;
    #pragma unroll
    for (int w = 0; w < 4; ++w) waveBase += (w < wid) ? ws[w] : 0;
    int off0 = blockOff[b] + waveBase + (P - p);
    if (i0 < n) out[i0] = off0;
    if (i1 < n) out[i1] = off0 + x0;
}

// ---------------------------------------------------------------------------
// Partition pass 2: write (key,other) pairs to per-(bucket,block) runs.
// LDS-atomic cursors only; runs contiguous & L2-resident.
// ---------------------------------------------------------------------------
__global__ __launch_bounds__(256) void part_scatter_kernel(
    const int* __restrict__ es, const int* __restrict__ ed,
    const int* __restrict__ baseD, const int* __restrict__ baseG,
    int2* __restrict__ pairD, int2* __restrict__ pairG,
    int ne, int shiftD, int shiftG)
{
    __shared__ int curD[256], curG[256];
    const int tid = threadIdx.x;
    curD[tid] = baseD[tid * NB1 + blockIdx.x];
    curG[tid] = baseG[tid * NB1 + blockIdx.x];
    __syncthreads();
    const int chunk = (ne + NB1 - 1) / NB1;
    const int e0 = blockIdx.x * chunk;
    const int e1 = min(e0 + chunk, ne);
    for (int e = e0 + tid; e < e1; e += 256) {
        int s = es[e], d = ed[e];
        int pD = atomicAdd(&curD[d >> shiftD], 1);
        pairD[pD] = make_int2(d, s);
        int pG = atomicAdd(&curG[s >> shiftG], 1);
        pairG[pG] = make_int2(s, d);
    }
}

// ---------------------------------------------------------------------------
// CSR finalize: one block per bucket. LDS hist -> LDS scan -> row[]; second
// sweep ranks with LDS atomics, writes idx[]. No global atomics.
// ---------------------------------------------------------------------------
__global__ __launch_bounds__(256) void csr_build_kernel(
    const int2* __restrict__ pairD, const int* __restrict__ baseD,
    int* __restrict__ rowD, int* __restrict__ idxD, int nd, int shiftD, int nbktD,
    const int2* __restrict__ pairG, const int* __restrict__ baseG,
    int* __restrict__ rowG, int* __restrict__ idxG, int ng, int shiftG, int nbktG)
{
    __shared__ int lcnt[512], lcur[512];
    __shared__ int ws[4];
    const int j = blockIdx.x & 255;
    const int isG = blockIdx.x >> 8;
    const int2* pair; const int* base; int* row; int* idx; int n, shift, nbkt;
    if (isG) { pair = pairG; base = baseG; row = rowG; idx = idxG; n = ng; shift = shiftG; nbkt = nbktG; }
    else     { pair = pairD; base = baseD; row = rowD; idx = idxD; n = nd; shift = shiftD; nbkt = nbktD; }
    if (j >= nbkt) return;

    const int tid = threadIdx.x;
    const int nLo = j << shift;
    const int nHi = min(nLo + (1 << shift), n);
    const int range = nHi - nLo;               // <= 512
    const int segBase = base[j * NB1];
    const int segEnd  = base[(j + 1) * NB1];

    lcnt[tid] = 0; lcnt[tid + 256] = 0;
    __syncthreads();
    for (int t = segBase + tid; t < segEnd; t += 256)
        atomicAdd(&lcnt[pair[t].x - nLo], 1);
    __syncthreads();

    int i0 = 2 * tid, i1 = i0 + 1;
    int c0 = (i0 < range) ? lcnt[i0] : 0;
    int c1 = (i1 < range) ? lcnt[i1] : 0;
    int p = c0 + c1;
    int P = p;
    const int lane = tid & 63, wid = tid >> 6;
    #pragma unroll
    for (int off = 1; off < 64; off <<= 1) {
        int u = __shfl_up(P, off, 64);
        if (lane >= off) P += u;
    }
    if (lane == 63) ws[wid] = P;
    __syncthreads();
    int waveBase = 0;
    #pragma unroll
    for (int w = 0; w < 4; ++w) waveBase += (w < wid) ? ws[w] : 0;
    int o0 = segBase + waveBase + (P - p);
    int o1 = o0 + c0;
    if (i0 < range) { row[nLo + i0] = o0; lcur[i0] = o0; }
    if (i1 < range) { row[nLo + i1] = o1; lcur[i1] = o1; }
    if (nHi == n && tid == 0) row[n] = segEnd;
    __syncthreads();

    for (int t = segBase + tid; t < segEnd; t += 256) {
        int2 pr = pair[t];
        int pos = atomicAdd(&lcur[pr.x - nLo], 1);
        idx[pos] = pr.y;
    }
}

// ---------------------------------------------------------------------------
// Gather-mean over bf16 rows. HALF-WAVE (32 lanes) per node:
//   lane = 32*half + 8*sub + c8; sub = edge slot (4 in flight), c8 = uint4
//   slot within the 128 B row (8 bf16 channels per lane).
// One wave-level load instruction covers 8 edge-rows. fp32 accumulate,
// 2-stage xor reduce (m=8,16 — stays within the 32-lane half), fp32 out.
// ---------------------------------------------------------------------------
__global__ __launch_bounds__(256) void gather_mean_kernel(
    const u16* __restrict__ srcD, const u16* __restrict__ srcG,
    const int* __restrict__ rowD, const int* __restrict__ idxD,
    const int* __restrict__ rowG, const int* __restrict__ idxG,
    float* __restrict__ outD, float* __restrict__ outG, int nd, int ng)
{
    int hw = blockIdx.x * 8 + (threadIdx.x >> 5);   // half-wave id = node
    int l5 = threadIdx.x & 31;
    const u16* src; const int* row; const int* idx; float* out; int node;
    if (hw < nd)            { src = srcD; row = rowD; idx = idxD; out = outD; node = hw; }
    else if (hw < nd + ng)  { src = srcG; row = rowG; idx = idxG; out = outG; node = hw - nd; }
    else return;

    const int sub = l5 >> 3;        // 0..3: edge slot
    const int c8 = l5 & 7;          // uint4 index within row
    int beg = row[node], end = row[node + 1];

    float a0[8], a1[8];
    #pragma unroll
    for (int j = 0; j < 8; ++j) { a0[j] = 0.f; a1[j] = 0.f; }

    int i = beg;
    for (; i + 8 <= end; i += 8) {
        int s0 = idx[i + sub];
        int s1 = idx[i + 4 + sub];
        uint4 v0 = *((const uint4*)(src + (size_t)s0 * H) + c8);
        uint4 v1 = *((const uint4*)(src + (size_t)s1 * H) + c8);
        a0[0] += bflo(v0.x); a0[1] += bfhi(v0.x); a0[2] += bflo(v0.y); a0[3] += bfhi(v0.y);
        a0[4] += bflo(v0.z); a0[5] += bfhi(v0.z); a0[6] += bflo(v0.w); a0[7] += bfhi(v0.w);
        a1[0] += bflo(v1.x); a1[1] += bfhi(v1.x); a1[2] += bflo(v1.y); a1[3] += bfhi(v1.y);
        a1[4] += bflo(v1.z); a1[5] += bfhi(v1.z); a1[6] += bflo(v1.w); a1[7] += bfhi(v1.w);
    }
    if (i + 4 <= end) {
        int s0 = idx[i + sub];
        uint4 v0 = *((const uint4*)(src + (size_t)s0 * H) + c8);
        a0[0] += bflo(v0.x); a0[1] += bfhi(v0.x); a0[2] += bflo(v0.y); a0[3] += bfhi(v0.y);
        a0[4] += bflo(v0.z); a0[5] += bfhi(v0.z); a0[6] += bflo(v0.w); a0[7] += bfhi(v0.w);
        i += 4;
    }
    if (i + sub < end) {
        int s1 = idx[i + sub];
        uint4 v1 = *((const uint4*)(src + (size_t)s1 * H) + c8);
        a1[0] += bflo(v1.x); a1[1] += bfhi(v1.x); a1[2] += bflo(v1.y); a1[3] += bfhi(v1.y);
        a1[4] += bflo(v1.z); a1[5] += bfhi(v1.z); a1[6] += bflo(v1.w); a1[7] += bfhi(v1.w);
    }
    float acc[8];
    #pragma unroll
    for (int j = 0; j < 8; ++j) acc[j] = a0[j] + a1[j];
    #pragma unroll
    for (int j = 0; j < 8; ++j) {
        acc[j] += __shfl_xor(acc[j], 8, 64);
        acc[j] += __shfl_xor(acc[j], 16, 64);
    }
    if (sub == 0) {
        float inv = 1.0f / fmaxf((float)(end - beg), 1.0f);
        float4 o0 = make_float4(acc[0] * inv, acc[1] * inv, acc[2] * inv, acc[3] * inv);
        float4 o1 = make_float4(acc[4] * inv, acc[5] * inv, acc[6] * inv, acc[7] * inv);
        float* dst = &out[(size_t)node * H + c8 * 8];
        *(float4*)dst = o0;
        *(float4*)(dst + 4) = o1;
    }
}

// ---------------------------------------------------------------------------
// SAGE linear, BOTH directions in one dispatch (block-role split):
// out_bf16 = act(mean @ wl + x @ wr + b). mean fp32; x fp32 (L1) or bf16 (L2).
// ---------------------------------------------------------------------------
template <bool RELU, bool XBF16>
__global__ __launch_bounds__(256) void sage_mm_kernel(
    const float* __restrict__ meanD, const void* __restrict__ xD,
    u16* __restrict__ outD,
    const float* __restrict__ wlD, const float* __restrict__ wrD,
    const float* __restrict__ bD, int nd,
    const float* __restrict__ meanG, const void* __restrict__ xG,
    u16* __restrict__ outG,
    const float* __restrict__ wlG, const float* __restrict__ wrG,
    const float* __restrict__ bG, int ng, int MBD)
{
    __shared__ float sWl[H * H];
    __shared__ float sWr[H * H];
    __shared__ float sMean[16][H];
    __shared__ float sX[16][H];

    int b = blockIdx.x;
    const float* mean; const void* xdst; u16* outBf;
    const float* wl; const float* wr; const float* bias; int n;
    if (b < MBD) { mean = meanD; xdst = xD; outBf = outD; wl = wlD; wr = wrD; bias = bD; n = nd; }
    else { b -= MBD; mean = meanG; xdst = xG; outBf = outG; wl = wlG; wr = wrG; bias = bG; n = ng; }

    const int col = threadIdx.x & 63;
    const int quad = threadIdx.x >> 6;
    for (int i = threadIdx.x; i < H * H; i += 256) {
        sWl[i] = wl[i];
        sWr[i] = wr[i];
    }
    const int row0 = b * 16;
    for (int r = quad; r < 16; r += 4) {
        int row = row0 + r;
        if (row < n) {
            sMean[r][col] = mean[(size_t)row * H + col];
            if (XBF16) {
                const u16* xb = (const u16*)xdst;
                sX[r][col] = bfu(xb[(size_t)row * H + col]);
            } else {
                const float* xf = (const float*)xdst;
                sX[r][col] = xf[(size_t)row * H + col];
            }
        }
    }
    __syncthreads();

    float o[4];
    o[0] = o[1] = o[2] = o[3] = bias[col];
    #pragma unroll 4
    for (int k = 0; k < H; k += 4) {
        float wl0 = sWl[(k + 0) * H + col], wr0 = sWr[(k + 0) * H + col];
        float wl1 = sWl[(k + 1) * H + col], wr1 = sWr[(k + 1) * H + col];
        float wl2 = sWl[(k + 2) * H + col], wr2 = sWr[(k + 2) * H + col];
        float wl3 = sWl[(k + 3) * H + col], wr3 = sWr[(k + 3) * H + col];
        #pragma unroll
        for (int r = 0; r < 4; ++r) {
            float4 m  = *(const float4*)&sMean[quad + 4 * r][k];
            float4 xx = *(const float4*)&sX[quad + 4 * r][k];
            o[r] += m.x * wl0 + m.y * wl1 + m.z * wl2 + m.w * wl3
                  + xx.x * wr0 + xx.y * wr1 + xx.z * wr2 + xx.w * wr3;
        }
    }
    #pragma unroll
    for (int r = 0; r < 4; ++r) {
        int row = row0 + quad + r * 4;
        if (row < n) {
            float v = o[r];
            if (RELU) v = fmaxf(v, 0.0f);
            outBf[(size_t)row * H + col] = bf16rne(v);
        }
    }
}

// ---------------------------------------------------------------------------
// Classifier on bf16 rows: 8 lanes per edge, uint4 loads (one load instr
// covers 8 rows), fp32 dot, 3-stage xor reduce within the 8-lane group.
// ---------------------------------------------------------------------------
__global__ __launch_bounds__(256) void classify_kernel(
    const u16* __restrict__ hg2, const u16* __restrict__ hd2,
    const int* __restrict__ ls, const int* __restrict__ ld,
    float* __restrict__ out, int nl)
{
    long long t = (long long)blockIdx.x * blockDim.x + threadIdx.x;
    int e = (int)(t >> 3);
    int c8 = (int)(t & 7);
    if (e >= nl) return;
    int a = ls[e];
    int b = ld[e];
    uint4 ua = *((const uint4*)(hg2 + (size_t)a * H) + c8);
    uint4 ub = *((const uint4*)(hd2 + (size_t)b * H) + c8);
    float v = bflo(ua.x) * bflo(ub.x) + bfhi(ua.x) * bfhi(ub.x)
            + bflo(ua.y) * bflo(ub.y) + bfhi(ua.y) * bfhi(ub.y)
            + bflo(ua.z) * bflo(ub.z) + bfhi(ua.z) * bfhi(ub.z)
            + bflo(ua.w) * bflo(ub.w) + bfhi(ua.w) * bfhi(ub.w);
    v += __shfl_xor(v, 1, 64);
    v += __shfl_xor(v, 2, 64);
    v += __shfl_xor(v, 4, 64);
    if (c8 == 0) out[e] = v;
}

extern "C" void kernel_launch(void* const* d_in, const int* in_sizes, int n_in,
                              void* d_out, int out_size, void* d_ws, size_t ws_size,
                              hipStream_t stream)
{
    const float* gene  = (const float*)d_in[0];
    const float* dis   = (const float*)d_in[1];
    const float* w1gdl = (const float*)d_in[2];
    const float* w1gdr = (const float*)d_in[3];
    const float* w1dgl = (const float*)d_in[4];
    const float* w1dgr = (const float*)d_in[5];
    const float* w2gdl = (const float*)d_in[6];
    const float* w2gdr = (const float*)d_in[7];
    const float* w2dgl = (const float*)d_in[8];
    const float* w2dgr = (const float*)d_in[9];
    const float* b1gd  = (const float*)d_in[10];
    const float* b1dg  = (const float*)d_in[11];
    const float* b2gd  = (const float*)d_in[12];
    const float* b2dg  = (const float*)d_in[13];
    const int* es = (const int*)d_in[14];
    const int* ed = (const int*)d_in[15];
    const int* ls = (const int*)d_in[16];
    const int* ld = (const int*)d_in[17];

    const int ng = in_sizes[0] / H;   // 100000
    const int nd = in_sizes[1] / H;   // 30000
    const int ne = in_sizes[14];      // 1500000
    const int nl = in_sizes[16];      // 500000

    int shiftD = 0; while (((nd + (1 << shiftD) - 1) >> shiftD) > 256) ++shiftD;  // 7
    int shiftG = 0; while (((ng + (1 << shiftG) - 1) >> shiftG) > 256) ++shiftG;  // 9
    const int nbktD = (nd + (1 << shiftD) - 1) >> shiftD;
    const int nbktG = (ng + (1 << shiftG) - 1) >> shiftG;
    const int n1 = 256 * NB1;

    // --- Workspace layout ---
    int* rowD = (int*)d_ws;                         // nd+1
    int* rowG = rowD + nd + 1;                      // ng+1
    int* idxD = rowG + ng + 1;                      // ne
    int* idxG = idxD + ne;                          // ne
    u16* geneBf = (u16*)(idxG + ne);                // ng*H
    u16* disBf  = geneBf + (size_t)ng * H;          // nd*H
    u16* h1Dbf  = disBf + (size_t)nd * H;           // nd*H
    u16* h1Gbf  = h1Dbf + (size_t)nd * H;           // ng*H
    u16* h2Dbf  = h1Gbf + (size_t)ng * H;           // nd*H
    u16* h2Gbf  = h2Dbf + (size_t)nd * H;           // ng*H
    uintptr_t p = (uintptr_t)(h2Gbf + (size_t)ng * H);
    p = (p + 15) & ~(uintptr_t)15;
    // Union region: CSR-build scratch (dead after csr_build) aliased w/ means.
    float* MD = (float*)p;                          // nd*H
    float* MG = MD + (size_t)nd * H;                // ng*H
    int* histD = (int*)p;                           // n1
    int* histG = histD + n1;                        // n1
    int* baseD = histG + n1;                        // n1+1
    int* baseG = baseD + n1 + 1;                    // n1+1
    int* partial  = baseG + n1 + 1;                 // 1024
    int* blockOff = partial + 1024;                 // 1024
    uintptr_t pp = (uintptr_t)(blockOff + 1024);
    pp = (pp + 15) & ~(uintptr_t)15;
    int2* pairD = (int2*)pp;                        // ne
    int2* pairG = pairD + ne;                       // ne

    // --- Fused: partition histogram || bf16 conversion ---
    const long long na4 = (long long)ng * H / 4;
    const long long nb4 = (long long)nd * H / 4;
    const int convBlocks = (int)((na4 + nb4 + 255) / 256);
    fused_count_convert_kernel<<<NB1 + convBlocks, 256, 0, stream>>>(
        es, ed, histD, histG, ne, shiftD, shiftG,
        gene, geneBf, na4, dis, disBf, nb4);

    // --- Scan -> cursors ---
    const int B1 = n1 / SCAN_CHUNK;          // 256
    const int nbtot = 2 * B1;                // 512
    scan_reduce_kernel<<<nbtot, 256, 0, stream>>>(histD, n1, histG, n1, B1, partial);
    scan_partials_kernel<<<1, 1024, 0, stream>>>(partial, blockOff, B1, nbtot,
                                                 baseD, n1, baseG, n1);
    scan_apply_kernel<<<nbtot, 256, 0, stream>>>(histD, baseD, n1,
                                                 histG, baseG, n1, B1, blockOff);
    part_scatter_kernel<<<NB1, 256, 0, stream>>>(es, ed, baseD, baseG,
                                                 pairD, pairG, ne, shiftD, shiftG);
    csr_build_kernel<<<512, 256, 0, stream>>>(
        pairD, baseD, rowD, idxD, nd, shiftD, nbktD,
        pairG, baseG, rowG, idxG, ng, shiftG, nbktG);

    const int gatherBlocks = (nd + ng + 7) / 8;
    const int MBD = (nd + 15) / 16;
    const int MBG = (ng + 15) / 16;

    // Layer 1
    gather_mean_kernel<<<gatherBlocks, 256, 0, stream>>>(
        geneBf, disBf, rowD, idxD, rowG, idxG, MD, MG, nd, ng);
    sage_mm_kernel<true, false><<<MBD + MBG, 256, 0, stream>>>(
        MD, dis, h1Dbf, w1gdl, w1gdr, b1gd, nd,
        MG, gene, h1Gbf, w1dgl, w1dgr, b1dg, ng, MBD);

    // Layer 2
    gather_mean_kernel<<<gatherBlocks, 256, 0, stream>>>(
        h1Gbf, h1Dbf, rowD, idxD, rowG, idxG, MD, MG, nd, ng);
    sage_mm_kernel<false, true><<<MBD + MBG, 256, 0, stream>>>(
        MD, h1Dbf, h2Dbf, w2gdl, w2gdr, b2gd, nd,
        MG, h1Gbf, h2Gbf, w2dgl, w2dgr, b2dg, ng, MBD);

    // Classifier
    {
        long long threads = (long long)nl * 8;
        int blocks = (int)((threads + 255) / 256);
        classify_kernel<<<blocks, 256, 0, stream>>>(h2Gbf, h2Dbf, ls, ld,
                                                    (float*)d_out, nl);
    }
}

// Round 8
// 372.080 us; speedup vs baseline: 5.5324x; 1.3044x over previous
//
#include <hip/hip_runtime.h>
#include <hip/hip_bf16.h>

#define H 64
#define SCAN_CHUNK 512
#define NB1 512          // partition blocks (per-(bucket,block) hist = 256*NB1)

typedef unsigned short u16;
typedef unsigned int u32;
typedef __attribute__((ext_vector_type(8))) __bf16 bf16x8;
typedef __attribute__((ext_vector_type(4))) float f32x4;

__device__ __forceinline__ float bflo(u32 u) {
    return __builtin_bit_cast(float, u << 16);
}
__device__ __forceinline__ float bfhi(u32 u) {
    return __builtin_bit_cast(float, u & 0xffff0000u);
}
__device__ __forceinline__ u16 bf16rne(float f) {
    u32 u = __builtin_bit_cast(u32, f);
    return (u16)((u + 0x7FFFu + ((u >> 16) & 1u)) >> 16);
}

// ---------------------------------------------------------------------------
// Fused: blocks [0,NB1) = partition histogram (LDS atomics, bucket-major out);
// blocks [NB1,...) = fp32->bf16 table conversion (pure BW, rides along).
// ---------------------------------------------------------------------------
__global__ __launch_bounds__(256) void fused_count_convert_kernel(
    const int* __restrict__ es, const int* __restrict__ ed,
    int* __restrict__ histD, int* __restrict__ histG,
    int ne, int shiftD, int shiftG,
    const float* __restrict__ a, u16* __restrict__ oa, long long na4,
    const float* __restrict__ b, u16* __restrict__ ob, long long nb4)
{
    if (blockIdx.x < NB1) {
        __shared__ int lhd[256], lhg[256];
        const int tid = threadIdx.x;
        lhd[tid] = 0; lhg[tid] = 0;
        __syncthreads();
        const int chunk = (ne + NB1 - 1) / NB1;
        const int e0 = blockIdx.x * chunk;
        const int e1 = min(e0 + chunk, ne);
        for (int e = e0 + tid; e < e1; e += 256) {
            atomicAdd(&lhd[ed[e] >> shiftD], 1);
            atomicAdd(&lhg[es[e] >> shiftG], 1);
        }
        __syncthreads();
        histD[tid * NB1 + blockIdx.x] = lhd[tid];
        histG[tid * NB1 + blockIdx.x] = lhg[tid];
        return;
    }
    long long i = (long long)(blockIdx.x - NB1) * 256 + threadIdx.x;
    const float* src; u16* dst; long long q;
    if (i < na4) { src = a; dst = oa; q = i; }
    else if (i < na4 + nb4) { src = b; dst = ob; q = i - na4; }
    else return;
    float4 v = *(const float4*)&src[q * 4];
    ushort4 o;
    o.x = bf16rne(v.x); o.y = bf16rne(v.y);
    o.z = bf16rne(v.z); o.w = bf16rne(v.w);
    *(ushort4*)&dst[q * 4] = o;
}

// ---------------------------------------------------------------------------
// Scan phase A: per-block reduce of SCAN_CHUNK elements (2 segments).
// ---------------------------------------------------------------------------
__global__ __launch_bounds__(256) void scan_reduce_kernel(
    const int* __restrict__ a1, int n1, const int* __restrict__ a2, int n2,
    int B1, int* __restrict__ partial)
{
    const int b = blockIdx.x;
    const int* a; int n, base;
    if (b < B1) { a = a1; n = n1; base = b * SCAN_CHUNK; }
    else        { a = a2; n = n2; base = (b - B1) * SCAN_CHUNK; }
    int t = threadIdx.x;
    int i0 = base + 2 * t, i1 = i0 + 1;
    int v = ((i0 < n) ? a[i0] : 0) + ((i1 < n) ? a[i1] : 0);
    #pragma unroll
    for (int off = 32; off > 0; off >>= 1) v += __shfl_down(v, off, 64);
    __shared__ int ws[4];
    if ((t & 63) == 0) ws[t >> 6] = v;
    __syncthreads();
    if (t == 0) partial[b] = ws[0] + ws[1] + ws[2] + ws[3];
}

// ---------------------------------------------------------------------------
// Scan phase B: one block scans all partials (<=1024), 2 segments.
// ---------------------------------------------------------------------------
__global__ __launch_bounds__(1024) void scan_partials_kernel(
    const int* __restrict__ partial, int* __restrict__ blockOff,
    int B1, int nbtot,
    int* __restrict__ out1, int n1, int* __restrict__ out2, int n2)
{
    __shared__ int sA[1024], sB[1024];
    int t = threadIdx.x;
    int x = (t < nbtot) ? partial[t] : 0;
    sA[t] = x;
    __syncthreads();
    int* cur = sA; int* nxt = sB;
    for (int off = 1; off < 1024; off <<= 1) {
        int v = cur[t];
        if (t >= off) v += cur[t - off];
        nxt[t] = v;
        __syncthreads();
        int* tmp = cur; cur = nxt; nxt = tmp;
    }
    int incl = cur[t];
    int excl = incl - x;
    int tot1 = cur[B1 - 1];
    if (t < nbtot) blockOff[t] = excl - ((t >= B1) ? tot1 : 0);
    if (t == 0) out1[n1] = tot1;
    if (t == nbtot - 1) out2[n2] = incl - tot1;
}

// ---------------------------------------------------------------------------
// Scan phase C: per-block exclusive scan; writes cursor arrays.
// ---------------------------------------------------------------------------
__global__ __launch_bounds__(256) void scan_apply_kernel(
    const int* __restrict__ a1, int* __restrict__ out1, int n1,
    const int* __restrict__ a2, int* __restrict__ out2, int n2,
    int B1, const int* __restrict__ blockOff)
{
    const int b = blockIdx.x;
    const int* a; int* out; int n, base;
    if (b < B1) { a = a1; out = out1; n = n1; base = b * SCAN_CHUNK; }
    else        { a = a2; out = out2; n = n2; base = (b - B1) * SCAN_CHUNK; }
    int t = threadIdx.x;
    int lane = t & 63, wid = t >> 6;
    int i0 = base + 2 * t, i1 = i0 + 1;
    int x0 = (i0 < n) ? a[i0] : 0;
    int x1 = (i1 < n) ? a[i1] : 0;
    int p = x0 + x1;
    int P = p;
    #pragma unroll
    for (int off = 1; off < 64; off <<= 1) {
        int u = __shfl_up(P, off, 64);
        if (lane >= off) P += u;
    }
    __shared__ int ws[4];
    if (lane == 63) ws[wid] = P;
    __syncthreads();
    int waveBase = 0;
    #pragma unroll
    for (int w = 0; w < 4; ++w) waveBase += (w < wid) ? ws[w] : 0;
    int off0 = blockOff[b] + waveBase + (P - p);
    if (i0 < n) out[i0] = off0;
    if (i1 < n) out[i1] = off0 + x0;
}

// ---------------------------------------------------------------------------
// Partition pass 2: write (key,other) pairs to per-(bucket,block) runs.
// LDS-atomic cursors only; runs contiguous & L2-resident.
// ---------------------------------------------------------------------------
__global__ __launch_bounds__(256) void part_scatter_kernel(
    const int* __restrict__ es, const int* __restrict__ ed,
    const int* __restrict__ baseD, const int* __restrict__ baseG,
    int2* __restrict__ pairD, int2* __restrict__ pairG,
    int ne, int shiftD, int shiftG)
{
    __shared__ int curD[256], curG[256];
    const int tid = threadIdx.x;
    curD[tid] = baseD[tid * NB1 + blockIdx.x];
    curG[tid] = baseG[tid * NB1 + blockIdx.x];
    __syncthreads();
    const int chunk = (ne + NB1 - 1) / NB1;
    const int e0 = blockIdx.x * chunk;
    const int e1 = min(e0 + chunk, ne);
    for (int e = e0 + tid; e < e1; e += 256) {
        int s = es[e], d = ed[e];
        int pD = atomicAdd(&curD[d >> shiftD], 1);
        pairD[pD] = make_int2(d, s);
        int pG = atomicAdd(&curG[s >> shiftG], 1);
        pairG[pG] = make_int2(s, d);
    }
}

// ---------------------------------------------------------------------------
// CSR finalize: one block per bucket. LDS hist -> LDS scan -> row[]; second
// sweep ranks with LDS atomics, writes idx[]. No global atomics.
// ---------------------------------------------------------------------------
__global__ __launch_bounds__(256) void csr_build_kernel(
    const int2* __restrict__ pairD, const int* __restrict__ baseD,
    int* __restrict__ rowD, int* __restrict__ idxD, int nd, int shiftD, int nbktD,
    const int2* __restrict__ pairG, const int* __restrict__ baseG,
    int* __restrict__ rowG, int* __restrict__ idxG, int ng, int shiftG, int nbktG)
{
    __shared__ int lcnt[512], lcur[512];
    __shared__ int ws[4];
    const int j = blockIdx.x & 255;
    const int isG = blockIdx.x >> 8;
    const int2* pair; const int* base; int* row; int* idx; int n, shift, nbkt;
    if (isG) { pair = pairG; base = baseG; row = rowG; idx = idxG; n = ng; shift = shiftG; nbkt = nbktG; }
    else     { pair = pairD; base = baseD; row = rowD; idx = idxD; n = nd; shift = shiftD; nbkt = nbktD; }
    if (j >= nbkt) return;

    const int tid = threadIdx.x;
    const int nLo = j << shift;
    const int nHi = min(nLo + (1 << shift), n);
    const int range = nHi - nLo;               // <= 512
    const int segBase = base[j * NB1];
    const int segEnd  = base[(j + 1) * NB1];

    lcnt[tid] = 0; lcnt[tid + 256] = 0;
    __syncthreads();
    for (int t = segBase + tid; t < segEnd; t += 256)
        atomicAdd(&lcnt[pair[t].x - nLo], 1);
    __syncthreads();

    int i0 = 2 * tid, i1 = i0 + 1;
    int c0 = (i0 < range) ? lcnt[i0] : 0;
    int c1 = (i1 < range) ? lcnt[i1] : 0;
    int p = c0 + c1;
    int P = p;
    const int lane = tid & 63, wid = tid >> 6;
    #pragma unroll
    for (int off = 1; off < 64; off <<= 1) {
        int u = __shfl_up(P, off, 64);
        if (lane >= off) P += u;
    }
    if (lane == 63) ws[wid] = P;
    __syncthreads();
    int waveBase = 0;
    #pragma unroll
    for (int w = 0; w < 4; ++w) waveBase += (w < wid) ? ws[w] : 0;
    int o0 = segBase + waveBase + (P - p);
    int o1 = o0 + c0;
    if (i0 < range) { row[nLo + i0] = o0; lcur[i0] = o0; }
    if (i1 < range) { row[nLo + i1] = o1; lcur[i1] = o1; }
    if (nHi == n && tid == 0) row[n] = segEnd;
    __syncthreads();

    for (int t = segBase + tid; t < segEnd; t += 256) {
        int2 pr = pair[t];
        int pos = atomicAdd(&lcur[pr.x - nLo], 1);
        idx[pos] = pr.y;
    }
}

// ---------------------------------------------------------------------------
// Gather-mean over bf16 rows -> bf16 means. HALF-WAVE (32 lanes) per node:
// lane = 32*half + 8*sub + c8; 4 edge slots in flight, uint4 loads.
// fp32 accumulate, 2-stage xor reduce, bf16 packed 16 B store.
// ---------------------------------------------------------------------------
__global__ __launch_bounds__(256) void gather_mean_kernel(
    const u16* __restrict__ srcD, const u16* __restrict__ srcG,
    const int* __restrict__ rowD, const int* __restrict__ idxD,
    const int* __restrict__ rowG, const int* __restrict__ idxG,
    u16* __restrict__ outD, u16* __restrict__ outG, int nd, int ng)
{
    int hw = blockIdx.x * 8 + (threadIdx.x >> 5);   // half-wave id = node
    int l5 = threadIdx.x & 31;
    const u16* src; const int* row; const int* idx; u16* out; int node;
    if (hw < nd)            { src = srcD; row = rowD; idx = idxD; out = outD; node = hw; }
    else if (hw < nd + ng)  { src = srcG; row = rowG; idx = idxG; out = outG; node = hw - nd; }
    else return;

    const int sub = l5 >> 3;        // 0..3: edge slot
    const int c8 = l5 & 7;          // uint4 index within row
    int beg = row[node], end = row[node + 1];

    float a0[8], a1[8];
    #pragma unroll
    for (int j = 0; j < 8; ++j) { a0[j] = 0.f; a1[j] = 0.f; }

    int i = beg;
    for (; i + 8 <= end; i += 8) {
        int s0 = idx[i + sub];
        int s1 = idx[i + 4 + sub];
        uint4 v0 = *((const uint4*)(src + (size_t)s0 * H) + c8);
        uint4 v1 = *((const uint4*)(src + (size_t)s1 * H) + c8);
        a0[0] += bflo(v0.x); a0[1] += bfhi(v0.x); a0[2] += bflo(v0.y); a0[3] += bfhi(v0.y);
        a0[4] += bflo(v0.z); a0[5] += bfhi(v0.z); a0[6] += bflo(v0.w); a0[7] += bfhi(v0.w);
        a1[0] += bflo(v1.x); a1[1] += bfhi(v1.x); a1[2] += bflo(v1.y); a1[3] += bfhi(v1.y);
        a1[4] += bflo(v1.z); a1[5] += bfhi(v1.z); a1[6] += bflo(v1.w); a1[7] += bfhi(v1.w);
    }
    if (i + 4 <= end) {
        int s0 = idx[i + sub];
        uint4 v0 = *((const uint4*)(src + (size_t)s0 * H) + c8);
        a0[0] += bflo(v0.x); a0[1] += bfhi(v0.x); a0[2] += bflo(v0.y); a0[3] += bfhi(v0.y);
        a0[4] += bflo(v0.z); a0[5] += bfhi(v0.z); a0[6] += bflo(v0.w); a0[7] += bfhi(v0.w);
        i += 4;
    }
    if (i + sub < end) {
        int s1 = idx[i + sub];
        uint4 v1 = *((const uint4*)(src + (size_t)s1 * H) + c8);
        a1[0] += bflo(v1.x); a1[1] += bfhi(v1.x); a1[2] += bflo(v1.y); a1[3] += bfhi(v1.y);
        a1[4] += bflo(v1.z); a1[5] += bfhi(v1.z); a1[6] += bflo(v1.w); a1[7] += bfhi(v1.w);
    }
    float acc[8];
    #pragma unroll
    for (int j = 0; j < 8; ++j) acc[j] = a0[j] + a1[j];
    #pragma unroll
    for (int j = 0; j < 8; ++j) {
        acc[j] += __shfl_xor(acc[j], 8, 64);
        acc[j] += __shfl_xor(acc[j], 16, 64);
    }
    if (sub == 0) {
        float inv = 1.0f / fmaxf((float)(end - beg), 1.0f);
        u32 w0 = (u32)bf16rne(acc[0] * inv) | ((u32)bf16rne(acc[1] * inv) << 16);
        u32 w1 = (u32)bf16rne(acc[2] * inv) | ((u32)bf16rne(acc[3] * inv) << 16);
        u32 w2 = (u32)bf16rne(acc[4] * inv) | ((u32)bf16rne(acc[5] * inv) << 16);
        u32 w3 = (u32)bf16rne(acc[6] * inv) | ((u32)bf16rne(acc[7] * inv) << 16);
        uint4 pk = make_uint4(w0, w1, w2, w3);
        *(uint4*)(out + (size_t)node * H + c8 * 8) = pk;
    }
}

// ---------------------------------------------------------------------------
// SAGE linear via MFMA, BOTH directions in one dispatch:
//   out_bf16 = act([mean | x](bf16) @ [wl; wr](bf16) + b)
// Block = 256 threads, 256 rows. Weights staged once into LDS in B-frag
// layout (bf16), held in 16 reg frags. Per wave: 4 row-tiles x 16
// mfma_f32_16x16x32_bf16; bias in acc init; fp32 accumulate; bf16 store.
// Frag maps (measured, guide §3): A[m=lane&15][k=(lane>>4)*8+j];
// B[k=(lane>>4)*8+j][n=lane&15]; C/D col=lane&15, row=(lane>>4)*4+reg.
// ---------------------------------------------------------------------------
template <bool RELU>
__global__ __launch_bounds__(256) void sage_mm_mfma_kernel(
    const u16* __restrict__ meanD, const u16* __restrict__ xD, u16* __restrict__ outD,
    const float* __restrict__ wlD, const float* __restrict__ wrD,
    const float* __restrict__ bD, int nd,
    const u16* __restrict__ meanG, const u16* __restrict__ xG, u16* __restrict__ outG,
    const float* __restrict__ wlG, const float* __restrict__ wrG,
    const float* __restrict__ bG, int ng, int MBD)
{
    __shared__ u16 sB[16 * 64 * 8];   // [frag=c*4+t][lane][j]
    int b = blockIdx.x;
    const u16 *mean, *x; u16* out; const float *wl, *wr, *bias; int n;
    if (b < MBD) { mean = meanD; x = xD; out = outD; wl = wlD; wr = wrD; bias = bD; n = nd; }
    else { b -= MBD; mean = meanG; x = xG; out = outG; wl = wlG; wr = wrG; bias = bG; n = ng; }

    const int tid = threadIdx.x;
    // Stage W = [wl(64x64); wr(64x64)] -> B-frag bf16 layout.
    for (int i = tid; i < 4096; i += 256) {
        int k = i >> 6, ncol = i & 63;
        int q = (k >> 3) & 3, j = k & 7, t = ncol >> 4, n15 = ncol & 15;
        int lane = q * 16 + n15;
        int c0 = k >> 5;                     // 0..1
        sB[(((c0 + 0) * 4 + t) * 64 + lane) * 8 + j] = bf16rne(wl[i]);
        sB[(((c0 + 2) * 4 + t) * 64 + lane) * 8 + j] = bf16rne(wr[i]);
    }
    __syncthreads();

    const int lane = tid & 63;
    const int wave = tid >> 6;
    const int m = lane & 15;
    const int q = lane >> 4;

    bf16x8 Bf[16];
    {
        const uint4* sB4 = (const uint4*)sB;
        #pragma unroll
        for (int f = 0; f < 16; ++f)
            Bf[f] = __builtin_bit_cast(bf16x8, sB4[f * 64 + lane]);
    }
    float bv[4];
    #pragma unroll
    for (int t = 0; t < 4; ++t) bv[t] = bias[t * 16 + m];

    const int row0 = b * 256;
    #pragma unroll
    for (int r = 0; r < 4; ++r) {
        int rbase = row0 + (wave + 4 * r) * 16;   // wave-uniform
        if (rbase >= n) break;
        int gr = min(rbase + m, n - 1);
        const uint4* mrow = (const uint4*)(mean + (size_t)gr * H);
        const uint4* xrow = (const uint4*)(x + (size_t)gr * H);
        bf16x8 A0 = __builtin_bit_cast(bf16x8, mrow[q]);       // k 0..31
        bf16x8 A1 = __builtin_bit_cast(bf16x8, mrow[q + 4]);   // k 32..63
        bf16x8 A2 = __builtin_bit_cast(bf16x8, xrow[q]);
        bf16x8 A3 = __builtin_bit_cast(bf16x8, xrow[q + 4]);
        f32x4 acc[4];
        #pragma unroll
        for (int t = 0; t < 4; ++t) acc[t] = (f32x4){bv[t], bv[t], bv[t], bv[t]};
        #pragma unroll
        for (int t = 0; t < 4; ++t) {
            acc[t] = __builtin_amdgcn_mfma_f32_16x16x32_bf16(A0, Bf[0 * 4 + t], acc[t], 0, 0, 0);
            acc[t] = __builtin_amdgcn_mfma_f32_16x16x32_bf16(A1, Bf[1 * 4 + t], acc[t], 0, 0, 0);
            acc[t] = __builtin_amdgcn_mfma_f32_16x16x32_bf16(A2, Bf[2 * 4 + t], acc[t], 0, 0, 0);
            acc[t] = __builtin_amdgcn_mfma_f32_16x16x32_bf16(A3, Bf[3 * 4 + t], acc[t], 0, 0, 0);
        }
        #pragma unroll
        for (int reg = 0; reg < 4; ++reg) {
            int orow = rbase + q * 4 + reg;
            if (orow < n) {
                u16* op = out + (size_t)orow * H;
                #pragma unroll
                for (int t = 0; t < 4; ++t) {
                    float v = acc[t][reg];
                    if (RELU) v = fmaxf(v, 0.0f);
                    op[t * 16 + m] = bf16rne(v);
                }
            }
        }
    }
}

// ---------------------------------------------------------------------------
// Classifier on bf16 rows: 8 lanes per edge, uint4 loads, fp32 dot,
// 3-stage xor reduce within the 8-lane group.
// ---------------------------------------------------------------------------
__global__ __launch_bounds__(256) void classify_kernel(
    const u16* __restrict__ hg2, const u16* __restrict__ hd2,
    const int* __restrict__ ls, const int* __restrict__ ld,
    float* __restrict__ out, int nl)
{
    long long t = (long long)blockIdx.x * blockDim.x + threadIdx.x;
    int e = (int)(t >> 3);
    int c8 = (int)(t & 7);
    if (e >= nl) return;
    int a = ls[e];
    int b = ld[e];
    uint4 ua = *((const uint4*)(hg2 + (size_t)a * H) + c8);
    uint4 ub = *((const uint4*)(hd2 + (size_t)b * H) + c8);
    float v = bflo(ua.x) * bflo(ub.x) + bfhi(ua.x) * bfhi(ub.x)
            + bflo(ua.y) * bflo(ub.y) + bfhi(ua.y) * bfhi(ub.y)
            + bflo(ua.z) * bflo(ub.z) + bfhi(ua.z) * bfhi(ub.z)
            + bflo(ua.w) * bflo(ub.w) + bfhi(ua.w) * bfhi(ub.w);
    v += __shfl_xor(v, 1, 64);
    v += __shfl_xor(v, 2, 64);
    v += __shfl_xor(v, 4, 64);
    if (c8 == 0) out[e] = v;
}

extern "C" void kernel_launch(void* const* d_in, const int* in_sizes, int n_in,
                              void* d_out, int out_size, void* d_ws, size_t ws_size,
                              hipStream_t stream)
{
    const float* gene  = (const float*)d_in[0];
    const float* dis   = (const float*)d_in[1];
    const float* w1gdl = (const float*)d_in[2];
    const float* w1gdr = (const float*)d_in[3];
    const float* w1dgl = (const float*)d_in[4];
    const float* w1dgr = (const float*)d_in[5];
    const float* w2gdl = (const float*)d_in[6];
    const float* w2gdr = (const float*)d_in[7];
    const float* w2dgl = (const float*)d_in[8];
    const float* w2dgr = (const float*)d_in[9];
    const float* b1gd  = (const float*)d_in[10];
    const float* b1dg  = (const float*)d_in[11];
    const float* b2gd  = (const float*)d_in[12];
    const float* b2dg  = (const float*)d_in[13];
    const int* es = (const int*)d_in[14];
    const int* ed = (const int*)d_in[15];
    const int* ls = (const int*)d_in[16];
    const int* ld = (const int*)d_in[17];

    const int ng = in_sizes[0] / H;   // 100000
    const int nd = in_sizes[1] / H;   // 30000
    const int ne = in_sizes[14];      // 1500000
    const int nl = in_sizes[16];      // 500000

    int shiftD = 0; while (((nd + (1 << shiftD) - 1) >> shiftD) > 256) ++shiftD;  // 7
    int shiftG = 0; while (((ng + (1 << shiftG) - 1) >> shiftG) > 256) ++shiftG;  // 9
    const int nbktD = (nd + (1 << shiftD) - 1) >> shiftD;
    const int nbktG = (ng + (1 << shiftG) - 1) >> shiftG;
    const int n1 = 256 * NB1;

    // --- Workspace layout ---
    int* rowD = (int*)d_ws;                         // nd+1
    int* rowG = rowD + nd + 1;                      // ng+1
    int* idxD = rowG + ng + 1;                      // ne
    int* idxG = idxD + ne;                          // ne
    u16* geneBf = (u16*)(idxG + ne);                // ng*H
    u16* disBf  = geneBf + (size_t)ng * H;          // nd*H
    u16* h1Dbf  = disBf + (size_t)nd * H;           // nd*H
    u16* h1Gbf  = h1Dbf + (size_t)nd * H;           // ng*H
    u16* h2Dbf  = h1Gbf + (size_t)ng * H;           // nd*H
    u16* h2Gbf  = h2Dbf + (size_t)nd * H;           // ng*H
    uintptr_t p = (uintptr_t)(h2Gbf + (size_t)ng * H);
    p = (p + 15) & ~(uintptr_t)15;
    // Union region: CSR-build scratch (dead after csr_build) aliased w/ means.
    u16* MD = (u16*)p;                              // nd*H bf16 means
    u16* MG = MD + (size_t)nd * H;                  // ng*H
    int* histD = (int*)p;                           // n1
    int* histG = histD + n1;                        // n1
    int* baseD = histG + n1;                        // n1+1
    int* baseG = baseD + n1 + 1;                    // n1+1
    int* partial  = baseG + n1 + 1;                 // 1024
    int* blockOff = partial + 1024;                 // 1024
    uintptr_t pp = (uintptr_t)(blockOff + 1024);
    pp = (pp + 15) & ~(uintptr_t)15;
    int2* pairD = (int2*)pp;                        // ne
    int2* pairG = pairD + ne;                       // ne

    // --- Fused: partition histogram || bf16 conversion ---
    const long long na4 = (long long)ng * H / 4;
    const long long nb4 = (long long)nd * H / 4;
    const int convBlocks = (int)((na4 + nb4 + 255) / 256);
    fused_count_convert_kernel<<<NB1 + convBlocks, 256, 0, stream>>>(
        es, ed, histD, histG, ne, shiftD, shiftG,
        gene, geneBf, na4, dis, disBf, nb4);

    // --- Scan -> cursors ---
    const int B1 = n1 / SCAN_CHUNK;          // 256
    const int nbtot = 2 * B1;                // 512
    scan_reduce_kernel<<<nbtot, 256, 0, stream>>>(histD, n1, histG, n1, B1, partial);
    scan_partials_kernel<<<1, 1024, 0, stream>>>(partial, blockOff, B1, nbtot,
                                                 baseD, n1, baseG, n1);
    scan_apply_kernel<<<nbtot, 256, 0, stream>>>(histD, baseD, n1,
                                                 histG, baseG, n1, B1, blockOff);
    part_scatter_kernel<<<NB1, 256, 0, stream>>>(es, ed, baseD, baseG,
                                                 pairD, pairG, ne, shiftD, shiftG);
    csr_build_kernel<<<512, 256, 0, stream>>>(
        pairD, baseD, rowD, idxD, nd, shiftD, nbktD,
        pairG, baseG, rowG, idxG, ng, shiftG, nbktG);

    const int gatherBlocks = (nd + ng + 7) / 8;
    const int MBD = (nd + 255) / 256;
    const int MBG = (ng + 255) / 256;

    // Layer 1
    gather_mean_kernel<<<gatherBlocks, 256, 0, stream>>>(
        geneBf, disBf, rowD, idxD, rowG, idxG, MD, MG, nd, ng);
    sage_mm_mfma_kernel<true><<<MBD + MBG, 256, 0, stream>>>(
        MD, disBf, h1Dbf, w1gdl, w1gdr, b1gd, nd,
        MG, geneBf, h1Gbf, w1dgl, w1dgr, b1dg, ng, MBD);

    // Layer 2
    gather_mean_kernel<<<gatherBlocks, 256, 0, stream>>>(
        h1Gbf, h1Dbf, rowD, idxD, rowG, idxG, MD, MG, nd, ng);
    sage_mm_mfma_kernel<false><<<MBD + MBG, 256, 0, stream>>>(
        MD, h1Dbf, h2Dbf, w2gdl, w2gdr, b2gd, nd,
        MG, h1Gbf, h2Gbf, w2dgl, w2dgr, b2dg, ng, MBD);

    // Classifier
    {
        long long threads = (long long)nl * 8;
        int blocks = (int)((threads + 255) / 256);
        classify_kernel<<<blocks, 256, 0, stream>>>(h2Gbf, h2Dbf, ls, ld,
                                                    (float*)d_out, nl);
    }
}